// Round 1
// baseline (2063.914 us; speedup 1.0000x reference)
//
#include <hip/hip_runtime.h>
#include <hip/hip_bf16.h>
#include <math.h>

#define NN 50000
#define NE 800000
#define NG 256
#define FHH 128
#define NL 6

// ---------------- graph-boundary search (batch_vec is sorted) ----------------
__global__ void k_gstart(const int* __restrict__ bv, int* __restrict__ gstart) {
  int g = blockIdx.x * blockDim.x + threadIdx.x;
  if (g > NG) return;
  int lo = 0, hi = NN;
  while (lo < hi) { int mid = (lo + hi) >> 1; if (bv[mid] < g) lo = mid + 1; else hi = mid; }
  gstart[g] = lo;
}

// ---------------- CSR build (by dst) ----------------
__global__ void k_deg(const int* __restrict__ dstv, int* __restrict__ deg) {
  int e = blockIdx.x * blockDim.x + threadIdx.x;
  if (e < NE) atomicAdd(&deg[dstv[e]], 1);
}

__global__ __launch_bounds__(1024) void k_scan(const int* __restrict__ deg,
                                               int* __restrict__ row_ptr,
                                               int* __restrict__ cursor) {
  __shared__ int buf[1024];
  __shared__ int carry_s;
  int t = threadIdx.x;
  if (t == 0) carry_s = 0;
  __syncthreads();
  for (int base = 0; base < NN; base += 1024) {
    int i = base + t;
    int v = (i < NN) ? deg[i] : 0;
    buf[t] = v;
    __syncthreads();
    for (int off = 1; off < 1024; off <<= 1) {
      int add = (t >= off) ? buf[t - off] : 0;
      __syncthreads();
      buf[t] += add;
      __syncthreads();
    }
    int incl = buf[t];
    int excl = incl - v;
    int c = carry_s;
    if (i < NN) { row_ptr[i] = c + excl; cursor[i] = c + excl; }
    __syncthreads();
    if (t == 1023) carry_s = c + incl;
    __syncthreads();
  }
  if (t == 0) row_ptr[NN] = carry_s;
}

__global__ void k_scatter(const int* __restrict__ srcv, const int* __restrict__ dstv,
                          int* __restrict__ cursor, int* __restrict__ col) {
  int e = blockIdx.x * blockDim.x + threadIdx.x;
  if (e < NE) {
    int d = dstv[e];
    int pos = atomicAdd(&cursor[d], 1);
    col[pos] = srcv[e];
  }
}

// ---------------- fused BN+ReLU + 4-way GEMM:  Y{q,k,v,s} = act(X) @ W + b ----------------
// grid: (ceil(N/64), 4); block 256.  Tile 64 rows x 128 cols, K-chunks of 32.
template <int K>
__global__ __launch_bounds__(256) void k_gemm(
    const float* __restrict__ X, int use_bn,
    const float* __restrict__ scale, const float* __restrict__ shift,
    const float* __restrict__ W0, const float* __restrict__ W1,
    const float* __restrict__ W2, const float* __restrict__ W3,
    const float* __restrict__ b0, const float* __restrict__ b1,
    const float* __restrict__ b2, const float* __restrict__ b3,
    float* __restrict__ Y0, float* __restrict__ Y1,
    float* __restrict__ Y2, float* __restrict__ Y3) {
  const int KB = 32;
  __shared__ float Xs[KB][65];    // transposed [k][row], padded
  __shared__ float Wb[KB][FHH];
  int t = threadIdx.x;
  int tx = t & 15, ty = t >> 4;   // 16x16 thread grid: 4 rows x 8 cols each
  int r0 = blockIdx.x * 64;
  int sel = blockIdx.y;
  const float* W = (sel == 0) ? W0 : (sel == 1) ? W1 : (sel == 2) ? W2 : W3;
  const float* bb = (sel == 0) ? b0 : (sel == 1) ? b1 : (sel == 2) ? b2 : b3;
  float* Y = (sel == 0) ? Y0 : (sel == 1) ? Y1 : (sel == 2) ? Y2 : Y3;

  float acc[4][8];
#pragma unroll
  for (int i = 0; i < 4; ++i)
#pragma unroll
    for (int j = 0; j < 8; ++j) acc[i][j] = 0.f;

  for (int kb = 0; kb < K; kb += KB) {
    // stage X tile 64x32, apply BN+ReLU on load, store transposed
#pragma unroll
    for (int j = 0; j < 2; ++j) {
      int id = t * 2 + j;          // 0..511
      int row = id >> 3;
      int kk4 = (id & 7) * 4;
      float4 val = make_float4(0.f, 0.f, 0.f, 0.f);
      int grow = r0 + row;
      if (grow < NN) val = *reinterpret_cast<const float4*>(X + (size_t)grow * K + kb + kk4);
      if (use_bn) {
        val.x = fmaxf(fmaf(val.x, scale[kb + kk4 + 0], shift[kb + kk4 + 0]), 0.f);
        val.y = fmaxf(fmaf(val.y, scale[kb + kk4 + 1], shift[kb + kk4 + 1]), 0.f);
        val.z = fmaxf(fmaf(val.z, scale[kb + kk4 + 2], shift[kb + kk4 + 2]), 0.f);
        val.w = fmaxf(fmaf(val.w, scale[kb + kk4 + 3], shift[kb + kk4 + 3]), 0.f);
      }
      Xs[kk4 + 0][row] = val.x;
      Xs[kk4 + 1][row] = val.y;
      Xs[kk4 + 2][row] = val.z;
      Xs[kk4 + 3][row] = val.w;
    }
    // stage W tile 32x128
#pragma unroll
    for (int j = 0; j < 4; ++j) {
      int id = t * 4 + j;          // 0..1023
      int kr = id >> 5;
      int c4 = (id & 31) * 4;
      *reinterpret_cast<float4*>(&Wb[kr][c4]) =
          *reinterpret_cast<const float4*>(W + (size_t)(kb + kr) * FHH + c4);
    }
    __syncthreads();
#pragma unroll
    for (int kk = 0; kk < KB; ++kk) {
      float aa[4];
      aa[0] = Xs[kk][ty * 4 + 0];
      aa[1] = Xs[kk][ty * 4 + 1];
      aa[2] = Xs[kk][ty * 4 + 2];
      aa[3] = Xs[kk][ty * 4 + 3];
      float4 bv0 = *reinterpret_cast<const float4*>(&Wb[kk][tx * 8]);
      float4 bv1 = *reinterpret_cast<const float4*>(&Wb[kk][tx * 8 + 4]);
      float bvv[8] = {bv0.x, bv0.y, bv0.z, bv0.w, bv1.x, bv1.y, bv1.z, bv1.w};
#pragma unroll
      for (int i = 0; i < 4; ++i)
#pragma unroll
        for (int j = 0; j < 8; ++j) acc[i][j] = fmaf(aa[i], bvv[j], acc[i][j]);
    }
    __syncthreads();
  }
#pragma unroll
  for (int i = 0; i < 4; ++i) {
    int grow = r0 + ty * 4 + i;
    if (grow < NN) {
      float4 o0, o1;
      o0.x = acc[i][0] + bb[tx * 8 + 0];
      o0.y = acc[i][1] + bb[tx * 8 + 1];
      o0.z = acc[i][2] + bb[tx * 8 + 2];
      o0.w = acc[i][3] + bb[tx * 8 + 3];
      o1.x = acc[i][4] + bb[tx * 8 + 4];
      o1.y = acc[i][5] + bb[tx * 8 + 5];
      o1.z = acc[i][6] + bb[tx * 8 + 6];
      o1.w = acc[i][7] + bb[tx * 8 + 7];
      *reinterpret_cast<float4*>(Y + (size_t)grow * FHH + tx * 8) = o0;
      *reinterpret_cast<float4*>(Y + (size_t)grow * FHH + tx * 8 + 4) = o1;
    }
  }
}

// ---------------- node-centric online-softmax attention aggregate ----------------
// block = 128 threads = one node; thread = feature f = h*16+c; 16-lane groups = heads.
__global__ __launch_bounds__(128) void k_agg(const float* __restrict__ q,
                                             const float* __restrict__ kmat,
                                             const float* __restrict__ vmat,
                                             const float* __restrict__ xs,
                                             const int* __restrict__ row_ptr,
                                             const int* __restrict__ col,
                                             float* __restrict__ y) {
  int n = blockIdx.x;
  int f = threadIdx.x;
  float qf = q[(size_t)n * FHH + f];
  int e0 = row_ptr[n], e1 = row_ptr[n + 1];
  float m = -INFINITY, sum = 0.f, acc = 0.f;
  for (int i = e0; i < e1; ++i) {
    int s = col[i];
    float kf = kmat[(size_t)s * FHH + f];
    float vf = vmat[(size_t)s * FHH + f];
    float p = qf * kf;
    p += __shfl_xor(p, 1, 16);
    p += __shfl_xor(p, 2, 16);
    p += __shfl_xor(p, 4, 16);
    p += __shfl_xor(p, 8, 16);
    float sc = p * 0.25f;                    // 1/sqrt(C), C=16
    float nm = fmaxf(m, sc);
    float r = __expf(m - nm);
    float w = __expf(sc - nm);
    sum = sum * r + w;
    acc = fmaf(acc, r, w * vf);
    m = nm;
  }
  float msg = acc / fmaxf(sum, 1e-16f);
  y[(size_t)n * FHH + f] = msg + xs[(size_t)n * FHH + f];
}

// ---------------- BN statistics (biased var over N) ----------------
__global__ __launch_bounds__(256) void k_bnstats(const float* __restrict__ y,
                                                 float* __restrict__ sums,
                                                 float* __restrict__ sumsq) {
  __shared__ float s1[256], s2[256];
  int f = threadIdx.x & 127;
  int half = threadIdx.x >> 7;
  float a = 0.f, b = 0.f;
  for (int r = blockIdx.x * 2 + half; r < NN; r += 512) {
    float val = y[(size_t)r * FHH + f];
    a += val;
    b += val * val;
  }
  s1[threadIdx.x] = a;
  s2[threadIdx.x] = b;
  __syncthreads();
  if (half == 0) {
    a += s1[threadIdx.x + 128];
    b += s2[threadIdx.x + 128];
    atomicAdd(&sums[f], a);
    atomicAdd(&sumsq[f], b);
  }
}

__global__ void k_bnfinal(const float* __restrict__ sums, const float* __restrict__ sumsq,
                          const float* __restrict__ gamma, const float* __restrict__ beta,
                          int layer, float* __restrict__ scale, float* __restrict__ shift) {
  int f = threadIdx.x;
  const float invn = 1.f / (float)NN;
  float mu = sums[f] * invn;
  float var = sumsq[f] * invn - mu * mu;
  float g = gamma[layer * FHH + f];
  float b = beta[layer * FHH + f];
  float sc = g * rsqrtf(var + 1e-5f);
  scale[f] = sc;
  shift[f] = b - mu * sc;
}

// ---------------- per-graph mean pooling of act(y) ----------------
__global__ __launch_bounds__(128) void k_pool(const float* __restrict__ y,
                                              const float* __restrict__ scale,
                                              const float* __restrict__ shift,
                                              const int* __restrict__ gstart,
                                              float* __restrict__ out, int layer) {
  int g = blockIdx.x;
  int f = threadIdx.x;
  int r0 = gstart[g], r1 = gstart[g + 1];
  float sc = scale[f], sh = shift[f];
  float s = 0.f;
  for (int r = r0; r < r1; ++r) s += fmaxf(fmaf(y[(size_t)r * FHH + f], sc, sh), 0.f);
  int cnt = r1 - r0;
  float p = s / (float)(cnt > 0 ? cnt : 1);
  if (layer < 5) {
    out[(size_t)g * 1024 + layer * FHH + f] = p;
  } else {  // SEL pads layer 5 into slots 5,6,7
    out[(size_t)g * 1024 + 5 * FHH + f] = p;
    out[(size_t)g * 1024 + 6 * FHH + f] = p;
    out[(size_t)g * 1024 + 7 * FHH + f] = p;
  }
}

extern "C" void kernel_launch(void* const* d_in, const int* in_sizes, int n_in,
                              void* d_out, int out_size, void* d_ws, size_t ws_size,
                              hipStream_t stream) {
  (void)in_sizes; (void)n_in; (void)out_size; (void)ws_size;
  const float* x    = (const float*)d_in[0];
  const int*   ei   = (const int*)d_in[1];
  const int*   bvec = (const int*)d_in[2];
  const float* Wq0  = (const float*)d_in[3];
  const float* bq0  = (const float*)d_in[4];
  const float* Wk0  = (const float*)d_in[5];
  const float* bk0  = (const float*)d_in[6];
  const float* Wv0  = (const float*)d_in[7];
  const float* bv0  = (const float*)d_in[8];
  const float* Ws0  = (const float*)d_in[9];
  const float* bs0  = (const float*)d_in[10];
  const float* WqS  = (const float*)d_in[11];
  const float* bqS  = (const float*)d_in[12];
  const float* WkS  = (const float*)d_in[13];
  const float* bkS  = (const float*)d_in[14];
  const float* WvS  = (const float*)d_in[15];
  const float* bvS  = (const float*)d_in[16];
  const float* WsS  = (const float*)d_in[17];
  const float* bsS  = (const float*)d_in[18];
  const float* gamma = (const float*)d_in[19];
  const float* beta  = (const float*)d_in[20];
  float* out = (float*)d_out;

  char* ws = (char*)d_ws;
  size_t off = 0;
  auto alloc = [&](size_t bytes) {
    void* p = ws + off;
    off = (off + bytes + 255) & ~(size_t)255;
    return p;
  };
  float* q   = (float*)alloc((size_t)NN * FHH * 4);
  float* kk  = (float*)alloc((size_t)NN * FHH * 4);
  float* vv  = (float*)alloc((size_t)NN * FHH * 4);
  float* xs  = (float*)alloc((size_t)NN * FHH * 4);
  float* y   = (float*)alloc((size_t)NN * FHH * 4);
  int* col     = (int*)alloc((size_t)NE * 4);
  int* row_ptr = (int*)alloc((size_t)(NN + 1) * 4);
  int* cursor  = (int*)alloc((size_t)NN * 4);
  int* deg     = (int*)alloc((size_t)NN * 4);
  int* gstart  = (int*)alloc((size_t)(NG + 1) * 4);
  float* bns   = (float*)alloc(FHH * 4);
  float* bnss  = (float*)alloc(FHH * 4);
  float* scale = (float*)alloc(FHH * 4);
  float* shift = (float*)alloc(FHH * 4);

  const int* srcv = ei;        // edge_index row 0
  const int* dstv = ei + NE;   // edge_index row 1

  hipMemsetAsync(deg, 0, (size_t)NN * 4, stream);
  k_gstart<<<5, 64, 0, stream>>>(bvec, gstart);
  k_deg<<<(NE + 255) / 256, 256, 0, stream>>>(dstv, deg);
  k_scan<<<1, 1024, 0, stream>>>(deg, row_ptr, cursor);
  k_scatter<<<(NE + 255) / 256, 256, 0, stream>>>(srcv, dstv, cursor, col);

  for (int l = 0; l < NL; ++l) {
    const float* Xin = (l == 0) ? x : y;
    int use_bn = (l == 0) ? 0 : 1;
    const float *Wq_, *Wk_, *Wv_, *Ws_, *bq_, *bk_, *bv_, *bs_;
    if (l == 0) {
      Wq_ = Wq0; Wk_ = Wk0; Wv_ = Wv0; Ws_ = Ws0;
      bq_ = bq0; bk_ = bk0; bv_ = bv0; bs_ = bs0;
    } else {
      size_t wo = (size_t)(l - 1) * FHH * FHH, bo = (size_t)(l - 1) * FHH;
      Wq_ = WqS + wo; Wk_ = WkS + wo; Wv_ = WvS + wo; Ws_ = WsS + wo;
      bq_ = bqS + bo; bk_ = bkS + bo; bv_ = bvS + bo; bs_ = bsS + bo;
    }
    dim3 gg((NN + 63) / 64, 4);
    if (l == 0)
      k_gemm<64><<<gg, 256, 0, stream>>>(Xin, use_bn, scale, shift,
                                         Wq_, Wk_, Wv_, Ws_, bq_, bk_, bv_, bs_,
                                         q, kk, vv, xs);
    else
      k_gemm<128><<<gg, 256, 0, stream>>>(Xin, use_bn, scale, shift,
                                          Wq_, Wk_, Wv_, Ws_, bq_, bk_, bv_, bs_,
                                          q, kk, vv, xs);
    k_agg<<<NN, 128, 0, stream>>>(q, kk, vv, xs, row_ptr, col, y);
    hipMemsetAsync(bns, 0, FHH * 4, stream);
    hipMemsetAsync(bnss, 0, FHH * 4, stream);
    k_bnstats<<<256, 256, 0, stream>>>(y, bns, bnss);
    k_bnfinal<<<1, FHH, 0, stream>>>(bns, bnss, gamma, beta, l, scale, shift);
    k_pool<<<NG, FHH, 0, stream>>>(y, scale, shift, gstart, out, l);
  }
}

// Round 2
// 1432.425 us; speedup vs baseline: 1.4409x; 1.4409x over previous
//
#include <hip/hip_runtime.h>
#include <hip/hip_bf16.h>
#include <math.h>

#define NN 50000
#define NE 800000
#define NG 256
#define FHH 128
#define NL 6
#define NCH 49   // ceil(50000/1024)

typedef __attribute__((ext_vector_type(8))) short s16x8;
typedef __attribute__((ext_vector_type(4))) float f32x4;

__device__ __forceinline__ ushort f2bf(float x) {
  uint u = __float_as_uint(x);
  u += 0x7fffu + ((u >> 16) & 1u);
  return (ushort)(u >> 16);
}
__device__ __forceinline__ float bf2f(ushort h) {
  return __uint_as_float(((uint)h) << 16);
}

// ---------------- graph-boundary search (batch_vec sorted) ----------------
__global__ void k_gstart(const int* __restrict__ bv, int* __restrict__ gstart) {
  int g = blockIdx.x * blockDim.x + threadIdx.x;
  if (g > NG) return;
  int lo = 0, hi = NN;
  while (lo < hi) { int mid = (lo + hi) >> 1; if (bv[mid] < g) lo = mid + 1; else hi = mid; }
  gstart[g] = lo;
}

// ---------------- CSR build (by dst) ----------------
__global__ void k_deg(const int* __restrict__ dstv, int* __restrict__ deg) {
  int e = blockIdx.x * blockDim.x + threadIdx.x;
  if (e < NE) atomicAdd(&deg[dstv[e]], 1);
}

__global__ __launch_bounds__(256) void k_scanA(const int* __restrict__ deg, int* __restrict__ part) {
  int b = blockIdx.x, t = threadIdx.x;
  int s = 0;
  for (int j = t; j < 1024; j += 256) { int i = b * 1024 + j; if (i < NN) s += deg[i]; }
  __shared__ int sh[4];
  for (int o = 32; o; o >>= 1) s += __shfl_down(s, o, 64);
  if ((t & 63) == 0) sh[t >> 6] = s;
  __syncthreads();
  if (t == 0) part[b] = sh[0] + sh[1] + sh[2] + sh[3];
}

__global__ void k_scanB(int* __restrict__ part, int* __restrict__ row_ptr) {
  if (threadIdx.x == 0 && blockIdx.x == 0) {
    int run = 0;
    for (int i = 0; i < NCH; ++i) { int v = part[i]; part[i] = run; run += v; }
    row_ptr[NN] = run;
  }
}

__global__ __launch_bounds__(1024) void k_scanC(const int* __restrict__ deg, const int* __restrict__ part,
                                                int* __restrict__ row_ptr, int* __restrict__ cursor) {
  __shared__ int buf[1024];
  int b = blockIdx.x, t = threadIdx.x;
  int i = b * 1024 + t;
  int v = (i < NN) ? deg[i] : 0;
  buf[t] = v;
  __syncthreads();
  for (int off = 1; off < 1024; off <<= 1) {
    int add = (t >= off) ? buf[t - off] : 0;
    __syncthreads();
    buf[t] += add;
    __syncthreads();
  }
  if (i < NN) { int ex = part[b] + buf[t] - v; row_ptr[i] = ex; cursor[i] = ex; }
}

__global__ void k_scatter(const int* __restrict__ srcv, const int* __restrict__ dstv,
                          int* __restrict__ cursor, int* __restrict__ col) {
  int e = blockIdx.x * blockDim.x + threadIdx.x;
  if (e < NE) {
    int d = dstv[e];
    int pos = atomicAdd(&cursor[d], 1);
    col[pos] = srcv[e];
  }
}

// ---------------- weight preconvert: f32 [K][128] -> split-bf16 tiled [kstep][col][32] ----------------
__global__ __launch_bounds__(256) void k_wconv0(const float* __restrict__ W0, const float* __restrict__ W1,
                                                const float* __restrict__ W2, const float* __restrict__ W3,
                                                ushort* __restrict__ wh, ushort* __restrict__ wl) {
  int id = blockIdx.x * 256 + threadIdx.x;           // 4*64*128 = 32768
  if (id >= 4 * 64 * 128) return;
  int mat = id >> 13, rem = id & 8191;
  int k = rem >> 7, c = rem & 127;
  const float* W = (mat == 0) ? W0 : (mat == 1) ? W1 : (mat == 2) ? W2 : W3;
  float v = W[k * 128 + c];
  ushort h = f2bf(v);
  ushort lo = f2bf(v - bf2f(h));
  size_t dst = (size_t)mat * 8192 + (size_t)(k >> 5) * 4096 + c * 32 + (k & 31);
  wh[dst] = h; wl[dst] = lo;
}

__global__ __launch_bounds__(256) void k_wconvS(const float* __restrict__ Wq, const float* __restrict__ Wk,
                                                const float* __restrict__ Wv, const float* __restrict__ Ws,
                                                ushort* __restrict__ wh, ushort* __restrict__ wl) {
  int id = blockIdx.x * 256 + threadIdx.x;           // 5*4*128*128 = 327680
  if (id >= 5 * 4 * 16384) return;
  int lay = id / 65536, rem = id % 65536;
  int mat = rem >> 14, rem2 = rem & 16383;
  int k = rem2 >> 7, c = rem2 & 127;
  const float* W = (mat == 0) ? Wq : (mat == 1) ? Wk : (mat == 2) ? Wv : Ws;
  float v = W[(size_t)lay * 16384 + k * 128 + c];
  ushort h = f2bf(v);
  ushort lo = f2bf(v - bf2f(h));
  size_t dst = 32768 + ((size_t)lay * 4 + mat) * 16384 + (size_t)(k >> 5) * 4096 + c * 32 + (k & 31);
  wh[dst] = h; wl[dst] = lo;
}

// ---------------- fused BN+ReLU + split-bf16 MFMA GEMM ----------------
// grid (ceil(N/128), 4 matrices), block 256 = 4 waves as 2x2 (64x64 per wave).
// 3-pass split: acc += ah*bh + al*bh + ah*bl  (al*bl dropped, ~2^-18 relative)
template <int K>
__global__ __launch_bounds__(256, 2) void k_gemm(
    const float* __restrict__ X, int use_bn,
    const float* __restrict__ scale, const float* __restrict__ shift,
    const ushort* __restrict__ Wth, const ushort* __restrict__ Wtl,
    const float* __restrict__ b0, const float* __restrict__ b1,
    const float* __restrict__ b2, const float* __restrict__ b3,
    float* __restrict__ Y0, float* __restrict__ Y1,
    float* __restrict__ Y2, float* __restrict__ Y3) {
  __shared__ __align__(16) ushort Ah[128][32];
  __shared__ __align__(16) ushort Al[128][32];
  __shared__ __align__(16) ushort Bh[4096];
  __shared__ __align__(16) ushort Bl[4096];
  int t = threadIdx.x;
  int mat = blockIdx.y;
  const ushort* wh = Wth + (size_t)mat * (K * 128);
  const ushort* wl = Wtl + (size_t)mat * (K * 128);
  const float* bb = (mat == 0) ? b0 : (mat == 1) ? b1 : (mat == 2) ? b2 : b3;
  float* Y = (mat == 0) ? Y0 : (mat == 1) ? Y1 : (mat == 2) ? Y2 : Y3;
  int r0 = blockIdx.x * 128;
  int lane = t & 63, w = t >> 6;
  int wr = w >> 1, wc = w & 1;
  int frow = lane & 15, fk = (lane >> 4) << 3;   // fragment row/col + k-chunk

  f32x4 acc[4][4];
#pragma unroll
  for (int i = 0; i < 4; ++i)
#pragma unroll
    for (int j = 0; j < 4; ++j)
#pragma unroll
      for (int r = 0; r < 4; ++r) acc[i][j][r] = 0.f;

  for (int kb = 0; kb < K; kb += 32) {
    // ---- stage A: 128 rows x 32 k, f32 -> BN/ReLU -> split bf16 ----
#pragma unroll
    for (int j = 0; j < 4; ++j) {
      int id = (t << 2) | j;           // 0..1023
      int row = id >> 3;
      int kk4 = (id & 7) << 2;
      int grow = r0 + row;
      float4 val = make_float4(0.f, 0.f, 0.f, 0.f);
      if (grow < NN) val = *reinterpret_cast<const float4*>(X + (size_t)grow * K + kb + kk4);
      if (use_bn) {
        float4 sc4 = *reinterpret_cast<const float4*>(scale + kb + kk4);
        float4 sh4 = *reinterpret_cast<const float4*>(shift + kb + kk4);
        val.x = fmaxf(fmaf(val.x, sc4.x, sh4.x), 0.f);
        val.y = fmaxf(fmaf(val.y, sc4.y, sh4.y), 0.f);
        val.z = fmaxf(fmaf(val.z, sc4.z, sh4.z), 0.f);
        val.w = fmaxf(fmaf(val.w, sc4.w, sh4.w), 0.f);
      }
      ushort h0 = f2bf(val.x), h1 = f2bf(val.y), h2 = f2bf(val.z), h3 = f2bf(val.w);
      ushort l0 = f2bf(val.x - bf2f(h0)), l1 = f2bf(val.y - bf2f(h1));
      ushort l2 = f2bf(val.z - bf2f(h2)), l3 = f2bf(val.w - bf2f(h3));
      *reinterpret_cast<uint2*>(&Ah[row][kk4]) =
          make_uint2((uint)h0 | ((uint)h1 << 16), (uint)h2 | ((uint)h3 << 16));
      *reinterpret_cast<uint2*>(&Al[row][kk4]) =
          make_uint2((uint)l0 | ((uint)l1 << 16), (uint)l2 | ((uint)l3 << 16));
    }
    // ---- stage B: contiguous 8KB tile copy (pre-tiled [col][32]) ----
    const ushort* wht = wh + (kb >> 5) * 4096;
    const ushort* wlt = wl + (kb >> 5) * 4096;
#pragma unroll
    for (int j = 0; j < 2; ++j) {
      int id = (t << 1) | j;           // 0..511
      *reinterpret_cast<int4*>(&Bh[id * 8]) = *reinterpret_cast<const int4*>(wht + id * 8);
      *reinterpret_cast<int4*>(&Bl[id * 8]) = *reinterpret_cast<const int4*>(wlt + id * 8);
    }
    __syncthreads();
    // ---- fragments + MFMA ----
    s16x8 ah[4], al[4], bh[4], bl[4];
#pragma unroll
    for (int g = 0; g < 4; ++g) {
      ah[g] = *reinterpret_cast<const s16x8*>(&Ah[wr * 64 + g * 16 + frow][fk]);
      al[g] = *reinterpret_cast<const s16x8*>(&Al[wr * 64 + g * 16 + frow][fk]);
      int colb = (wc * 64 + g * 16 + frow) * 32 + fk;
      bh[g] = *reinterpret_cast<const s16x8*>(&Bh[colb]);
      bl[g] = *reinterpret_cast<const s16x8*>(&Bl[colb]);
    }
#pragma unroll
    for (int rg = 0; rg < 4; ++rg)
#pragma unroll
      for (int cg = 0; cg < 4; ++cg) {
        acc[rg][cg] = __builtin_amdgcn_mfma_f32_16x16x32_bf16(ah[rg], bh[cg], acc[rg][cg], 0, 0, 0);
        acc[rg][cg] = __builtin_amdgcn_mfma_f32_16x16x32_bf16(al[rg], bh[cg], acc[rg][cg], 0, 0, 0);
        acc[rg][cg] = __builtin_amdgcn_mfma_f32_16x16x32_bf16(ah[rg], bl[cg], acc[rg][cg], 0, 0, 0);
      }
    __syncthreads();
  }
  // ---- epilogue: D[row=(l>>4)*4+r][col=l&15] + bias ----
  int qq = (lane >> 4) << 2;
#pragma unroll
  for (int rg = 0; rg < 4; ++rg) {
#pragma unroll
    for (int cg = 0; cg < 4; ++cg) {
      int colg = wc * 64 + cg * 16 + frow;
      float bv = bb[colg];
#pragma unroll
      for (int r = 0; r < 4; ++r) {
        int row = r0 + wr * 64 + rg * 16 + qq + r;
        if (row < NN) Y[(size_t)row * FHH + colg] = acc[rg][cg][r] + bv;
      }
    }
  }
}

// ---------------- node-centric online-softmax aggregate (unroll 2) ----------------
__global__ __launch_bounds__(128) void k_agg(const float* __restrict__ q,
                                             const float* __restrict__ kmat,
                                             const float* __restrict__ vmat,
                                             const float* __restrict__ xs,
                                             const int* __restrict__ row_ptr,
                                             const int* __restrict__ col,
                                             float* __restrict__ y) {
  int n = blockIdx.x;
  int f = threadIdx.x;
  float qf = q[(size_t)n * FHH + f];
  int e0 = row_ptr[n], e1 = row_ptr[n + 1];
  float m = -INFINITY, sum = 0.f, acc = 0.f;
  int i = e0;
  for (; i + 2 <= e1; i += 2) {
    int s0 = col[i], s1 = col[i + 1];
    float k0 = kmat[(size_t)s0 * FHH + f];
    float k1 = kmat[(size_t)s1 * FHH + f];
    float v0 = vmat[(size_t)s0 * FHH + f];
    float v1 = vmat[(size_t)s1 * FHH + f];
    float p0 = qf * k0, p1 = qf * k1;
    p0 += __shfl_xor(p0, 1, 16);  p1 += __shfl_xor(p1, 1, 16);
    p0 += __shfl_xor(p0, 2, 16);  p1 += __shfl_xor(p1, 2, 16);
    p0 += __shfl_xor(p0, 4, 16);  p1 += __shfl_xor(p1, 4, 16);
    p0 += __shfl_xor(p0, 8, 16);  p1 += __shfl_xor(p1, 8, 16);
    float sc0 = p0 * 0.25f, sc1 = p1 * 0.25f;
    float nm = fmaxf(m, fmaxf(sc0, sc1));
    float r = __expf(m - nm);
    float w0 = __expf(sc0 - nm), w1 = __expf(sc1 - nm);
    sum = fmaf(sum, r, w0 + w1);
    acc = fmaf(acc, r, fmaf(w0, v0, w1 * v1));
    m = nm;
  }
  if (i < e1) {
    int s0 = col[i];
    float k0 = kmat[(size_t)s0 * FHH + f];
    float v0 = vmat[(size_t)s0 * FHH + f];
    float p0 = qf * k0;
    p0 += __shfl_xor(p0, 1, 16);
    p0 += __shfl_xor(p0, 2, 16);
    p0 += __shfl_xor(p0, 4, 16);
    p0 += __shfl_xor(p0, 8, 16);
    float sc0 = p0 * 0.25f;
    float nm = fmaxf(m, sc0);
    float r = __expf(m - nm);
    float w0 = __expf(sc0 - nm);
    sum = fmaf(sum, r, w0);
    acc = fmaf(acc, r, w0 * v0);
    m = nm;
  }
  float msg = acc / fmaxf(sum, 1e-16f);
  y[(size_t)n * FHH + f] = msg + xs[(size_t)n * FHH + f];
}

// ---------------- BN statistics ----------------
__global__ __launch_bounds__(256) void k_bnstats(const float* __restrict__ y,
                                                 float* __restrict__ sums,
                                                 float* __restrict__ sumsq) {
  __shared__ float s1[256], s2[256];
  int f = threadIdx.x & 127;
  int half = threadIdx.x >> 7;
  float a = 0.f, b = 0.f;
  for (int r = blockIdx.x * 2 + half; r < NN; r += 512) {
    float val = y[(size_t)r * FHH + f];
    a += val;
    b += val * val;
  }
  s1[threadIdx.x] = a;
  s2[threadIdx.x] = b;
  __syncthreads();
  if (half == 0) {
    a += s1[threadIdx.x + 128];
    b += s2[threadIdx.x + 128];
    atomicAdd(&sums[f], a);
    atomicAdd(&sumsq[f], b);
  }
}

__global__ void k_bnfinal(const float* __restrict__ sums, const float* __restrict__ sumsq,
                          const float* __restrict__ gamma, const float* __restrict__ beta,
                          int layer, float* __restrict__ scale, float* __restrict__ shift) {
  int f = threadIdx.x;
  const float invn = 1.f / (float)NN;
  float mu = sums[f] * invn;
  float var = sumsq[f] * invn - mu * mu;
  float g = gamma[layer * FHH + f];
  float b = beta[layer * FHH + f];
  float sc = g * rsqrtf(var + 1e-5f);
  scale[f] = sc;
  shift[f] = b - mu * sc;
}

// ---------------- per-graph mean pooling of act(y), 4-way row split ----------------
__global__ __launch_bounds__(128) void k_pool(const float* __restrict__ y,
                                              const float* __restrict__ scale,
                                              const float* __restrict__ shift,
                                              const int* __restrict__ gstart,
                                              float* __restrict__ out, int layer) {
  int g = blockIdx.x;
  int part = blockIdx.y;
  int f = threadIdx.x;
  int r0 = gstart[g], r1 = gstart[g + 1];
  int len = r1 - r0;
  int q0 = r0 + (len * part) / 4;
  int q1 = r0 + (len * (part + 1)) / 4;
  float sc = scale[f], sh = shift[f];
  float s = 0.f;
  for (int r = q0; r < q1; ++r) s += fmaxf(fmaf(y[(size_t)r * FHH + f], sc, sh), 0.f);
  float p = s / (float)(len > 0 ? len : 1);
  if (layer < 5) {
    atomicAdd(&out[(size_t)g * 1024 + layer * FHH + f], p);
  } else {
    atomicAdd(&out[(size_t)g * 1024 + 5 * FHH + f], p);
    atomicAdd(&out[(size_t)g * 1024 + 6 * FHH + f], p);
    atomicAdd(&out[(size_t)g * 1024 + 7 * FHH + f], p);
  }
}

extern "C" void kernel_launch(void* const* d_in, const int* in_sizes, int n_in,
                              void* d_out, int out_size, void* d_ws, size_t ws_size,
                              hipStream_t stream) {
  (void)in_sizes; (void)n_in; (void)ws_size;
  const float* x    = (const float*)d_in[0];
  const int*   ei   = (const int*)d_in[1];
  const int*   bvec = (const int*)d_in[2];
  const float* Wq0  = (const float*)d_in[3];
  const float* bq0  = (const float*)d_in[4];
  const float* Wk0  = (const float*)d_in[5];
  const float* bk0  = (const float*)d_in[6];
  const float* Wv0  = (const float*)d_in[7];
  const float* bv0  = (const float*)d_in[8];
  const float* Ws0  = (const float*)d_in[9];
  const float* bs0  = (const float*)d_in[10];
  const float* WqS  = (const float*)d_in[11];
  const float* bqS  = (const float*)d_in[12];
  const float* WkS  = (const float*)d_in[13];
  const float* bkS  = (const float*)d_in[14];
  const float* WvS  = (const float*)d_in[15];
  const float* bvS  = (const float*)d_in[16];
  const float* WsS  = (const float*)d_in[17];
  const float* bsS  = (const float*)d_in[18];
  const float* gamma = (const float*)d_in[19];
  const float* beta  = (const float*)d_in[20];
  float* out = (float*)d_out;

  char* ws = (char*)d_ws;
  size_t off = 0;
  auto alloc = [&](size_t bytes) {
    void* p = ws + off;
    off = (off + bytes + 255) & ~(size_t)255;
    return p;
  };
  float* q   = (float*)alloc((size_t)NN * FHH * 4);
  float* kk  = (float*)alloc((size_t)NN * FHH * 4);
  float* vv  = (float*)alloc((size_t)NN * FHH * 4);
  float* xs  = (float*)alloc((size_t)NN * FHH * 4);
  float* y   = (float*)alloc((size_t)NN * FHH * 4);
  int* col     = (int*)alloc((size_t)NE * 4);
  int* row_ptr = (int*)alloc((size_t)(NN + 1) * 4);
  int* cursor  = (int*)alloc((size_t)NN * 4);
  int* deg     = (int*)alloc((size_t)NN * 4);
  int* part    = (int*)alloc((size_t)NCH * 4);
  int* gstart  = (int*)alloc((size_t)(NG + 1) * 4);
  float* bns   = (float*)alloc(FHH * 4);
  float* bnss  = (float*)alloc(FHH * 4);
  float* scale = (float*)alloc(FHH * 4);
  float* shift = (float*)alloc(FHH * 4);
  // split-bf16 weights: layer0 4*64*128, layers1-5 5*4*128*128 -> 360448 ushorts
  ushort* wsh = (ushort*)alloc((size_t)360448 * 2);
  ushort* wsl = (ushort*)alloc((size_t)360448 * 2);

  const int* srcv = ei;
  const int* dstv = ei + NE;

  hipMemsetAsync(out, 0, (size_t)out_size * 4, stream);
  hipMemsetAsync(deg, 0, (size_t)NN * 4, stream);
  k_gstart<<<5, 64, 0, stream>>>(bvec, gstart);
  k_deg<<<(NE + 255) / 256, 256, 0, stream>>>(dstv, deg);
  k_scanA<<<NCH, 256, 0, stream>>>(deg, part);
  k_scanB<<<1, 64, 0, stream>>>(part, row_ptr);
  k_scanC<<<NCH, 1024, 0, stream>>>(deg, part, row_ptr, cursor);
  k_scatter<<<(NE + 255) / 256, 256, 0, stream>>>(srcv, dstv, cursor, col);
  k_wconv0<<<128, 256, 0, stream>>>(Wq0, Wk0, Wv0, Ws0, wsh, wsl);
  k_wconvS<<<1280, 256, 0, stream>>>(WqS, WkS, WvS, WsS, wsh, wsl);

  for (int l = 0; l < NL; ++l) {
    const float* Xin = (l == 0) ? x : y;
    int use_bn = (l == 0) ? 0 : 1;
    const ushort* WthL = wsh + ((l == 0) ? 0 : (size_t)32768 + (size_t)(l - 1) * 65536);
    const ushort* WtlL = wsl + ((l == 0) ? 0 : (size_t)32768 + (size_t)(l - 1) * 65536);
    const float *bq_, *bk_, *bv_, *bs_;
    if (l == 0) { bq_ = bq0; bk_ = bk0; bv_ = bv0; bs_ = bs0; }
    else {
      size_t bo = (size_t)(l - 1) * FHH;
      bq_ = bqS + bo; bk_ = bkS + bo; bv_ = bvS + bo; bs_ = bsS + bo;
    }
    dim3 gg((NN + 127) / 128, 4);
    if (l == 0)
      k_gemm<64><<<gg, 256, 0, stream>>>(Xin, use_bn, scale, shift, WthL, WtlL,
                                         bq_, bk_, bv_, bs_, q, kk, vv, xs);
    else
      k_gemm<128><<<gg, 256, 0, stream>>>(Xin, use_bn, scale, shift, WthL, WtlL,
                                          bq_, bk_, bv_, bs_, q, kk, vv, xs);
    k_agg<<<NN, 128, 0, stream>>>(q, kk, vv, xs, row_ptr, col, y);
    hipMemsetAsync(bns, 0, FHH * 4, stream);
    hipMemsetAsync(bnss, 0, FHH * 4, stream);
    k_bnstats<<<256, 256, 0, stream>>>(y, bns, bnss);
    k_bnfinal<<<1, FHH, 0, stream>>>(bns, bnss, gamma, beta, l, scale, shift);
    dim3 pg(NG, 4);
    k_pool<<<pg, FHH, 0, stream>>>(y, scale, shift, gstart, out, l);
  }
}

// Round 3
// 1153.513 us; speedup vs baseline: 1.7892x; 1.2418x over previous
//
#include <hip/hip_runtime.h>
#include <hip/hip_bf16.h>
#include <math.h>

#define NN 50000
#define NE 800000
#define NG 256
#define FHH 128
#define NL 6
#define NCH 49   // ceil(50000/1024)

typedef __attribute__((ext_vector_type(8))) short s16x8;
typedef __attribute__((ext_vector_type(4))) float f32x4;

__device__ __forceinline__ ushort f2bf(float x) {
  uint u = __float_as_uint(x);
  u += 0x7fffu + ((u >> 16) & 1u);
  return (ushort)(u >> 16);
}
__device__ __forceinline__ float bf2f(ushort h) {
  return __uint_as_float(((uint)h) << 16);
}

// ---------------- graph-boundary search (batch_vec sorted) ----------------
__global__ void k_gstart(const int* __restrict__ bv, int* __restrict__ gstart) {
  int g = blockIdx.x * blockDim.x + threadIdx.x;
  if (g > NG) return;
  int lo = 0, hi = NN;
  while (lo < hi) { int mid = (lo + hi) >> 1; if (bv[mid] < g) lo = mid + 1; else hi = mid; }
  gstart[g] = lo;
}

// ---------------- CSR build (by dst) ----------------
__global__ void k_deg(const int* __restrict__ dstv, int* __restrict__ deg) {
  int e = blockIdx.x * blockDim.x + threadIdx.x;
  if (e < NE) atomicAdd(&deg[dstv[e]], 1);
}

__global__ __launch_bounds__(256) void k_scanA(const int* __restrict__ deg, int* __restrict__ part) {
  int b = blockIdx.x, t = threadIdx.x;
  int s = 0;
  for (int j = t; j < 1024; j += 256) { int i = b * 1024 + j; if (i < NN) s += deg[i]; }
  __shared__ int sh[4];
  for (int o = 32; o; o >>= 1) s += __shfl_down(s, o, 64);
  if ((t & 63) == 0) sh[t >> 6] = s;
  __syncthreads();
  if (t == 0) part[b] = sh[0] + sh[1] + sh[2] + sh[3];
}

__global__ void k_scanB(int* __restrict__ part, int* __restrict__ row_ptr) {
  if (threadIdx.x == 0 && blockIdx.x == 0) {
    int run = 0;
    for (int i = 0; i < NCH; ++i) { int v = part[i]; part[i] = run; run += v; }
    row_ptr[NN] = run;
  }
}

__global__ __launch_bounds__(1024) void k_scanC(const int* __restrict__ deg, const int* __restrict__ part,
                                                int* __restrict__ row_ptr, int* __restrict__ cursor) {
  __shared__ int buf[1024];
  int b = blockIdx.x, t = threadIdx.x;
  int i = b * 1024 + t;
  int v = (i < NN) ? deg[i] : 0;
  buf[t] = v;
  __syncthreads();
  for (int off = 1; off < 1024; off <<= 1) {
    int add = (t >= off) ? buf[t - off] : 0;
    __syncthreads();
    buf[t] += add;
    __syncthreads();
  }
  if (i < NN) { int ex = part[b] + buf[t] - v; row_ptr[i] = ex; cursor[i] = ex; }
}

__global__ void k_scatter(const int* __restrict__ srcv, const int* __restrict__ dstv,
                          int* __restrict__ cursor, int* __restrict__ col) {
  int e = blockIdx.x * blockDim.x + threadIdx.x;
  if (e < NE) {
    int d = dstv[e];
    int pos = atomicAdd(&cursor[d], 1);
    col[pos] = srcv[e];
  }
}

// ---------------- weight preconvert: f32 [K][128] -> split-bf16 tiled [kstep][col][32] ----------------
__global__ __launch_bounds__(256) void k_wconv0(const float* __restrict__ W0, const float* __restrict__ W1,
                                                const float* __restrict__ W2, const float* __restrict__ W3,
                                                ushort* __restrict__ wh, ushort* __restrict__ wl) {
  int id = blockIdx.x * 256 + threadIdx.x;           // 4*64*128 = 32768
  if (id >= 4 * 64 * 128) return;
  int mat = id >> 13, rem = id & 8191;
  int k = rem >> 7, c = rem & 127;
  const float* W = (mat == 0) ? W0 : (mat == 1) ? W1 : (mat == 2) ? W2 : W3;
  float v = W[k * 128 + c];
  ushort h = f2bf(v);
  ushort lo = f2bf(v - bf2f(h));
  size_t dst = (size_t)mat * 8192 + (size_t)(k >> 5) * 4096 + c * 32 + (k & 31);
  wh[dst] = h; wl[dst] = lo;
}

__global__ __launch_bounds__(256) void k_wconvS(const float* __restrict__ Wq, const float* __restrict__ Wk,
                                                const float* __restrict__ Wv, const float* __restrict__ Ws,
                                                ushort* __restrict__ wh, ushort* __restrict__ wl) {
  int id = blockIdx.x * 256 + threadIdx.x;           // 5*4*128*128 = 327680
  if (id >= 5 * 4 * 16384) return;
  int lay = id / 65536, rem = id % 65536;
  int mat = rem >> 14, rem2 = rem & 16383;
  int k = rem2 >> 7, c = rem2 & 127;
  const float* W = (mat == 0) ? Wq : (mat == 1) ? Wk : (mat == 2) ? Wv : Ws;
  float v = W[(size_t)lay * 16384 + k * 128 + c];
  ushort h = f2bf(v);
  ushort lo = f2bf(v - bf2f(h));
  size_t dst = 32768 + ((size_t)lay * 4 + mat) * 16384 + (size_t)(k >> 5) * 4096 + c * 32 + (k & 31);
  wh[dst] = h; wl[dst] = lo;
}

// ---------------- fused BN+ReLU + split-bf16 MFMA GEMM ----------------
// grid (ceil(N/128), 4 matrices), block 256 = 4 waves as 2x2 (64x64 per wave).
// 3-pass split: acc += ah*bh + al*bh + ah*bl
// mat 0 -> q (f32), mat 1 -> kv[:,0:128] bf16, mat 2 -> kv[:,128:256] bf16, mat 3 -> xs (f32)
template <int K>
__global__ __launch_bounds__(256, 2) void k_gemm(
    const float* __restrict__ X, int use_bn,
    const float* __restrict__ sums, const float* __restrict__ sumsq,
    const float* __restrict__ gvec, const float* __restrict__ bvec,
    const ushort* __restrict__ Wth, const ushort* __restrict__ Wtl,
    const float* __restrict__ b0, const float* __restrict__ b1,
    const float* __restrict__ b2, const float* __restrict__ b3,
    float* __restrict__ Yq, ushort* __restrict__ kv, float* __restrict__ Yxs) {
  __shared__ __align__(16) ushort Ah[128][32];
  __shared__ __align__(16) ushort Al[128][32];
  __shared__ __align__(16) ushort Bh[4096];
  __shared__ __align__(16) ushort Bl[4096];
  __shared__ float s_sc[128], s_sh[128];
  int t = threadIdx.x;
  int mat = blockIdx.y;
  const ushort* wh = Wth + (size_t)mat * (K * 128);
  const ushort* wl = Wtl + (size_t)mat * (K * 128);
  const float* bb = (mat == 0) ? b0 : (mat == 1) ? b1 : (mat == 2) ? b2 : b3;
  int r0 = blockIdx.x * 128;
  int lane = t & 63, w = t >> 6;
  int wr = w >> 1, wc = w & 1;
  int frow = lane & 15, fk = (lane >> 4) << 3;

  if (use_bn && t < 128) {
    const float invn = 1.f / (float)NN;
    float mu = sums[t] * invn;
    float var = sumsq[t] * invn - mu * mu;
    float sc = gvec[t] * rsqrtf(var + 1e-5f);
    s_sc[t] = sc;
    s_sh[t] = bvec[t] - mu * sc;
  }
  if (use_bn) __syncthreads();

  f32x4 acc[4][4];
#pragma unroll
  for (int i = 0; i < 4; ++i)
#pragma unroll
    for (int j = 0; j < 4; ++j)
#pragma unroll
      for (int r = 0; r < 4; ++r) acc[i][j][r] = 0.f;

  for (int kb = 0; kb < K; kb += 32) {
    // ---- stage A: 128 rows x 32 k, f32 -> BN/ReLU -> split bf16 ----
#pragma unroll
    for (int j = 0; j < 4; ++j) {
      int id = (t << 2) | j;           // 0..1023
      int row = id >> 3;
      int kk4 = (id & 7) << 2;
      int grow = r0 + row;
      float4 val = make_float4(0.f, 0.f, 0.f, 0.f);
      if (grow < NN) val = *reinterpret_cast<const float4*>(X + (size_t)grow * K + kb + kk4);
      if (use_bn) {
        val.x = fmaxf(fmaf(val.x, s_sc[kb + kk4 + 0], s_sh[kb + kk4 + 0]), 0.f);
        val.y = fmaxf(fmaf(val.y, s_sc[kb + kk4 + 1], s_sh[kb + kk4 + 1]), 0.f);
        val.z = fmaxf(fmaf(val.z, s_sc[kb + kk4 + 2], s_sh[kb + kk4 + 2]), 0.f);
        val.w = fmaxf(fmaf(val.w, s_sc[kb + kk4 + 3], s_sh[kb + kk4 + 3]), 0.f);
      }
      ushort h0 = f2bf(val.x), h1 = f2bf(val.y), h2 = f2bf(val.z), h3 = f2bf(val.w);
      ushort l0 = f2bf(val.x - bf2f(h0)), l1 = f2bf(val.y - bf2f(h1));
      ushort l2 = f2bf(val.z - bf2f(h2)), l3 = f2bf(val.w - bf2f(h3));
      *reinterpret_cast<uint2*>(&Ah[row][kk4]) =
          make_uint2((uint)h0 | ((uint)h1 << 16), (uint)h2 | ((uint)h3 << 16));
      *reinterpret_cast<uint2*>(&Al[row][kk4]) =
          make_uint2((uint)l0 | ((uint)l1 << 16), (uint)l2 | ((uint)l3 << 16));
    }
    // ---- stage B ----
    const ushort* wht = wh + (kb >> 5) * 4096;
    const ushort* wlt = wl + (kb >> 5) * 4096;
#pragma unroll
    for (int j = 0; j < 2; ++j) {
      int id = (t << 1) | j;           // 0..511
      *reinterpret_cast<int4*>(&Bh[id * 8]) = *reinterpret_cast<const int4*>(wht + id * 8);
      *reinterpret_cast<int4*>(&Bl[id * 8]) = *reinterpret_cast<const int4*>(wlt + id * 8);
    }
    __syncthreads();
    s16x8 ah[4], al[4], bh[4], bl[4];
#pragma unroll
    for (int g = 0; g < 4; ++g) {
      ah[g] = *reinterpret_cast<const s16x8*>(&Ah[wr * 64 + g * 16 + frow][fk]);
      al[g] = *reinterpret_cast<const s16x8*>(&Al[wr * 64 + g * 16 + frow][fk]);
      int colb = (wc * 64 + g * 16 + frow) * 32 + fk;
      bh[g] = *reinterpret_cast<const s16x8*>(&Bh[colb]);
      bl[g] = *reinterpret_cast<const s16x8*>(&Bl[colb]);
    }
#pragma unroll
    for (int rg = 0; rg < 4; ++rg)
#pragma unroll
      for (int cg = 0; cg < 4; ++cg) {
        acc[rg][cg] = __builtin_amdgcn_mfma_f32_16x16x32_bf16(ah[rg], bh[cg], acc[rg][cg], 0, 0, 0);
        acc[rg][cg] = __builtin_amdgcn_mfma_f32_16x16x32_bf16(al[rg], bh[cg], acc[rg][cg], 0, 0, 0);
        acc[rg][cg] = __builtin_amdgcn_mfma_f32_16x16x32_bf16(ah[rg], bl[cg], acc[rg][cg], 0, 0, 0);
      }
    __syncthreads();
  }
  // ---- epilogue: D[row=(l>>4)*4+r][col=l&15] + bias ----
  int qq = (lane >> 4) << 2;
#pragma unroll
  for (int rg = 0; rg < 4; ++rg) {
#pragma unroll
    for (int cg = 0; cg < 4; ++cg) {
      int colg = wc * 64 + cg * 16 + frow;
      float bv = bb[colg];
#pragma unroll
      for (int r = 0; r < 4; ++r) {
        int row = r0 + wr * 64 + rg * 16 + qq + r;
        if (row >= NN) continue;
        float val = acc[rg][cg][r] + bv;
        if (mat == 0)      Yq [(size_t)row * FHH + colg] = val;
        else if (mat == 3) Yxs[(size_t)row * FHH + colg] = val;
        else kv[(size_t)row * 256 + (mat == 2 ? 128 : 0) + colg] = f2bf(val);
      }
    }
  }
}

// ---------------- node-centric online-softmax aggregate, bf16 packed kv ----------------
// 64 lanes per node, 2 features/lane; 2 nodes per 128-thread block (one per wave).
__global__ __launch_bounds__(128) void k_agg(const float* __restrict__ q,
                                             const ushort* __restrict__ kv,
                                             const float* __restrict__ xs,
                                             const int* __restrict__ row_ptr,
                                             const int* __restrict__ col,
                                             float* __restrict__ y) {
  int n = blockIdx.x * 2 + (threadIdx.x >> 6);
  int t = threadIdx.x & 63;
  float2 qf = *reinterpret_cast<const float2*>(q + (size_t)n * FHH + 2 * t);
  int e0 = row_ptr[n], e1 = row_ptr[n + 1];
  float m = -INFINITY, sum = 0.f, a0 = 0.f, a1 = 0.f;
  int i = e0;
  for (; i + 2 <= e1; i += 2) {
    int s0 = col[i], s1 = col[i + 1];
    uint kp0 = *reinterpret_cast<const uint*>(kv + (size_t)s0 * 256 + 2 * t);
    uint kp1 = *reinterpret_cast<const uint*>(kv + (size_t)s1 * 256 + 2 * t);
    uint vp0 = *reinterpret_cast<const uint*>(kv + (size_t)s0 * 256 + 128 + 2 * t);
    uint vp1 = *reinterpret_cast<const uint*>(kv + (size_t)s1 * 256 + 128 + 2 * t);
    float p0 = qf.x * bf2f((ushort)kp0) + qf.y * bf2f((ushort)(kp0 >> 16));
    float p1 = qf.x * bf2f((ushort)kp1) + qf.y * bf2f((ushort)(kp1 >> 16));
    p0 += __shfl_xor(p0, 1, 8);  p1 += __shfl_xor(p1, 1, 8);
    p0 += __shfl_xor(p0, 2, 8);  p1 += __shfl_xor(p1, 2, 8);
    p0 += __shfl_xor(p0, 4, 8);  p1 += __shfl_xor(p1, 4, 8);
    float sc0 = p0 * 0.25f, sc1 = p1 * 0.25f;
    float nm = fmaxf(m, fmaxf(sc0, sc1));
    float r = __expf(m - nm);
    float w0 = __expf(sc0 - nm), w1 = __expf(sc1 - nm);
    sum = fmaf(sum, r, w0 + w1);
    a0 = fmaf(a0, r, fmaf(w0, bf2f((ushort)vp0), w1 * bf2f((ushort)vp1)));
    a1 = fmaf(a1, r, fmaf(w0, bf2f((ushort)(vp0 >> 16)), w1 * bf2f((ushort)(vp1 >> 16))));
    m = nm;
  }
  if (i < e1) {
    int s0 = col[i];
    uint kp0 = *reinterpret_cast<const uint*>(kv + (size_t)s0 * 256 + 2 * t);
    uint vp0 = *reinterpret_cast<const uint*>(kv + (size_t)s0 * 256 + 128 + 2 * t);
    float p0 = qf.x * bf2f((ushort)kp0) + qf.y * bf2f((ushort)(kp0 >> 16));
    p0 += __shfl_xor(p0, 1, 8);
    p0 += __shfl_xor(p0, 2, 8);
    p0 += __shfl_xor(p0, 4, 8);
    float sc0 = p0 * 0.25f;
    float nm = fmaxf(m, sc0);
    float r = __expf(m - nm);
    float w0 = __expf(sc0 - nm);
    sum = fmaf(sum, r, w0);
    a0 = fmaf(a0, r, w0 * bf2f((ushort)vp0));
    a1 = fmaf(a1, r, w0 * bf2f((ushort)(vp0 >> 16)));
    m = nm;
  }
  float inv = 1.f / fmaxf(sum, 1e-16f);
  float2 xv = *reinterpret_cast<const float2*>(xs + (size_t)n * FHH + 2 * t);
  float2 ov;
  ov.x = a0 * inv + xv.x;
  ov.y = a1 * inv + xv.y;
  *reinterpret_cast<float2*>(y + (size_t)n * FHH + 2 * t) = ov;
}

// ---------------- BN statistics ----------------
__global__ __launch_bounds__(256) void k_bnstats(const float* __restrict__ y,
                                                 float* __restrict__ sums,
                                                 float* __restrict__ sumsq) {
  __shared__ float s1[256], s2[256];
  int f = threadIdx.x & 127;
  int half = threadIdx.x >> 7;
  float a = 0.f, b = 0.f;
  for (int r = blockIdx.x * 2 + half; r < NN; r += 512) {
    float val = y[(size_t)r * FHH + f];
    a += val;
    b += val * val;
  }
  s1[threadIdx.x] = a;
  s2[threadIdx.x] = b;
  __syncthreads();
  if (half == 0) {
    a += s1[threadIdx.x + 128];
    b += s2[threadIdx.x + 128];
    atomicAdd(&sums[f], a);
    atomicAdd(&sumsq[f], b);
  }
}

// ---------------- per-graph mean pooling of act(y), 4-way row split ----------------
__global__ __launch_bounds__(128) void k_pool(const float* __restrict__ y,
                                              const float* __restrict__ sums,
                                              const float* __restrict__ sumsq,
                                              const float* __restrict__ gvec,
                                              const float* __restrict__ bvec,
                                              const int* __restrict__ gstart,
                                              float* __restrict__ out, int layer) {
  int g = blockIdx.x;
  int part = blockIdx.y;
  int f = threadIdx.x;
  const float invn = 1.f / (float)NN;
  float mu = sums[f] * invn;
  float var = sumsq[f] * invn - mu * mu;
  float sc = gvec[f] * rsqrtf(var + 1e-5f);
  float sh = bvec[f] - mu * sc;
  int r0 = gstart[g], r1 = gstart[g + 1];
  int len = r1 - r0;
  int q0 = r0 + (len * part) / 4;
  int q1 = r0 + (len * (part + 1)) / 4;
  float s = 0.f;
  for (int r = q0; r < q1; ++r) s += fmaxf(fmaf(y[(size_t)r * FHH + f], sc, sh), 0.f);
  float p = s / (float)(len > 0 ? len : 1);
  if (layer < 5) {
    atomicAdd(&out[(size_t)g * 1024 + layer * FHH + f], p);
  } else {
    atomicAdd(&out[(size_t)g * 1024 + 5 * FHH + f], p);
    atomicAdd(&out[(size_t)g * 1024 + 6 * FHH + f], p);
    atomicAdd(&out[(size_t)g * 1024 + 7 * FHH + f], p);
  }
}

extern "C" void kernel_launch(void* const* d_in, const int* in_sizes, int n_in,
                              void* d_out, int out_size, void* d_ws, size_t ws_size,
                              hipStream_t stream) {
  (void)in_sizes; (void)n_in; (void)ws_size;
  const float* x    = (const float*)d_in[0];
  const int*   ei   = (const int*)d_in[1];
  const int*   bvec = (const int*)d_in[2];
  const float* Wq0  = (const float*)d_in[3];
  const float* bq0  = (const float*)d_in[4];
  const float* Wk0  = (const float*)d_in[5];
  const float* bk0  = (const float*)d_in[6];
  const float* Wv0  = (const float*)d_in[7];
  const float* bv0  = (const float*)d_in[8];
  const float* Ws0  = (const float*)d_in[9];
  const float* bs0  = (const float*)d_in[10];
  const float* WqS  = (const float*)d_in[11];
  const float* bqS  = (const float*)d_in[12];
  const float* WkS  = (const float*)d_in[13];
  const float* bkS  = (const float*)d_in[14];
  const float* WvS  = (const float*)d_in[15];
  const float* bvS  = (const float*)d_in[16];
  const float* WsS  = (const float*)d_in[17];
  const float* bsS  = (const float*)d_in[18];
  const float* gamma = (const float*)d_in[19];
  const float* beta  = (const float*)d_in[20];
  float* out = (float*)d_out;

  char* ws = (char*)d_ws;
  size_t off = 0;
  auto alloc = [&](size_t bytes) {
    void* p = ws + off;
    off = (off + bytes + 255) & ~(size_t)255;
    return p;
  };
  float* q    = (float*)alloc((size_t)NN * FHH * 4);
  float* xs   = (float*)alloc((size_t)NN * FHH * 4);
  float* y    = (float*)alloc((size_t)NN * FHH * 4);
  ushort* kv  = (ushort*)alloc((size_t)NN * 256 * 2);
  int* col     = (int*)alloc((size_t)NE * 4);
  int* row_ptr = (int*)alloc((size_t)(NN + 1) * 4);
  int* cursor  = (int*)alloc((size_t)NN * 4);
  int* deg     = (int*)alloc((size_t)NN * 4);
  int* part    = (int*)alloc((size_t)NCH * 4);
  int* gstart  = (int*)alloc((size_t)(NG + 1) * 4);
  float* bstat = (float*)alloc((size_t)NL * 2 * FHH * 4);   // [layer][{sum,sumsq}][128]
  ushort* wsh = (ushort*)alloc((size_t)360448 * 2);
  ushort* wsl = (ushort*)alloc((size_t)360448 * 2);

  const int* srcv = ei;
  const int* dstv = ei + NE;

  hipMemsetAsync(out, 0, (size_t)out_size * 4, stream);
  hipMemsetAsync(deg, 0, (size_t)NN * 4, stream);
  hipMemsetAsync(bstat, 0, (size_t)NL * 2 * FHH * 4, stream);
  k_gstart<<<5, 64, 0, stream>>>(bvec, gstart);
  k_deg<<<(NE + 255) / 256, 256, 0, stream>>>(dstv, deg);
  k_scanA<<<NCH, 256, 0, stream>>>(deg, part);
  k_scanB<<<1, 64, 0, stream>>>(part, row_ptr);
  k_scanC<<<NCH, 1024, 0, stream>>>(deg, part, row_ptr, cursor);
  k_scatter<<<(NE + 255) / 256, 256, 0, stream>>>(srcv, dstv, cursor, col);
  k_wconv0<<<128, 256, 0, stream>>>(Wq0, Wk0, Wv0, Ws0, wsh, wsl);
  k_wconvS<<<1280, 256, 0, stream>>>(WqS, WkS, WvS, WsS, wsh, wsl);

  for (int l = 0; l < NL; ++l) {
    const float* Xin = (l == 0) ? x : y;
    int use_bn = (l == 0) ? 0 : 1;
    const ushort* WthL = wsh + ((l == 0) ? 0 : (size_t)32768 + (size_t)(l - 1) * 65536);
    const ushort* WtlL = wsl + ((l == 0) ? 0 : (size_t)32768 + (size_t)(l - 1) * 65536);
    const float *bq_, *bk_, *bv_, *bs_;
    if (l == 0) { bq_ = bq0; bk_ = bk0; bv_ = bv0; bs_ = bs0; }
    else {
      size_t bo = (size_t)(l - 1) * FHH;
      bq_ = bqS + bo; bk_ = bkS + bo; bv_ = bvS + bo; bs_ = bsS + bo;
    }
    // BN stats/params of previous layer's output feed this GEMM
    const float* psum = bstat + (size_t)(l - 1) * 2 * FHH;
    const float* psqs = psum + FHH;
    const float* pg = gamma + (size_t)(l - 1) * FHH;
    const float* pb = beta + (size_t)(l - 1) * FHH;
    dim3 gg((NN + 127) / 128, 4);
    if (l == 0)
      k_gemm<64><<<gg, 256, 0, stream>>>(Xin, 0, psum, psqs, pg, pb, WthL, WtlL,
                                         bq_, bk_, bv_, bs_, q, kv, xs);
    else
      k_gemm<128><<<gg, 256, 0, stream>>>(Xin, 1, psum, psqs, pg, pb, WthL, WtlL,
                                          bq_, bk_, bv_, bs_, q, kv, xs);
    k_agg<<<NN / 2, 128, 0, stream>>>(q, kv, xs, row_ptr, col, y);
    float* lsum = bstat + (size_t)l * 2 * FHH;
    float* lsqs = lsum + FHH;
    k_bnstats<<<256, 256, 0, stream>>>(y, lsum, lsqs);
    dim3 pg2(NG, 4);
    k_pool<<<pg2, FHH, 0, stream>>>(y, lsum, lsqs, gamma + (size_t)l * FHH,
                                    beta + (size_t)l * FHH, gstart, out, l);
  }
}

// Round 4
// 1118.625 us; speedup vs baseline: 1.8450x; 1.0312x over previous
//
#include <hip/hip_runtime.h>
#include <hip/hip_bf16.h>
#include <math.h>

#define NN 50000
#define NE 800000
#define NG 256
#define FHH 128
#define NL 6
#define NCH 49    // ceil(50000/1024)
#define NB 391    // ceil(50000/128) row-blocks

typedef __attribute__((ext_vector_type(8))) short s16x8;
typedef __attribute__((ext_vector_type(4))) float f32x4;

__device__ __forceinline__ ushort f2bf(float x) {
  uint u = __float_as_uint(x);
  u += 0x7fffu + ((u >> 16) & 1u);
  return (ushort)(u >> 16);
}
__device__ __forceinline__ float bf2f(ushort h) {
  return __uint_as_float(((uint)h) << 16);
}
__device__ __forceinline__ float bfl(uint u) { return __uint_as_float(u << 16); }
__device__ __forceinline__ float bfh(uint u) { return __uint_as_float(u & 0xffff0000u); }

__device__ __forceinline__ void gload16(const ushort* g, ushort* l) {
  __builtin_amdgcn_global_load_lds(
      (const __attribute__((address_space(1))) uint*)(const void*)g,
      (__attribute__((address_space(3))) uint*)(void*)l, 16, 0, 0);
}

// ---------------- graph-boundary search (batch_vec sorted) ----------------
__global__ void k_gstart(const int* __restrict__ bv, int* __restrict__ gstart) {
  int g = blockIdx.x * blockDim.x + threadIdx.x;
  if (g > NG) return;
  int lo = 0, hi = NN;
  while (lo < hi) { int mid = (lo + hi) >> 1; if (bv[mid] < g) lo = mid + 1; else hi = mid; }
  gstart[g] = lo;
}

// ---------------- CSR build (by dst) ----------------
__global__ void k_deg(const int* __restrict__ dstv, int* __restrict__ deg) {
  int e = blockIdx.x * blockDim.x + threadIdx.x;
  if (e < NE) atomicAdd(&deg[dstv[e]], 1);
}

__global__ __launch_bounds__(256) void k_scanA(const int* __restrict__ deg, int* __restrict__ part) {
  int b = blockIdx.x, t = threadIdx.x;
  int s = 0;
  for (int j = t; j < 1024; j += 256) { int i = b * 1024 + j; if (i < NN) s += deg[i]; }
  __shared__ int sh[4];
  for (int o = 32; o; o >>= 1) s += __shfl_down(s, o, 64);
  if ((t & 63) == 0) sh[t >> 6] = s;
  __syncthreads();
  if (t == 0) part[b] = sh[0] + sh[1] + sh[2] + sh[3];
}

__global__ void k_scanB(int* __restrict__ part, int* __restrict__ row_ptr) {
  if (threadIdx.x == 0 && blockIdx.x == 0) {
    int run = 0;
    for (int i = 0; i < NCH; ++i) { int v = part[i]; part[i] = run; run += v; }
    row_ptr[NN] = run;
  }
}

__global__ __launch_bounds__(1024) void k_scanC(const int* __restrict__ deg, const int* __restrict__ part,
                                                int* __restrict__ row_ptr, int* __restrict__ cursor) {
  __shared__ int buf[1024];
  int b = blockIdx.x, t = threadIdx.x;
  int i = b * 1024 + t;
  int v = (i < NN) ? deg[i] : 0;
  buf[t] = v;
  __syncthreads();
  for (int off = 1; off < 1024; off <<= 1) {
    int add = (t >= off) ? buf[t - off] : 0;
    __syncthreads();
    buf[t] += add;
    __syncthreads();
  }
  if (i < NN) { int ex = part[b] + buf[t] - v; row_ptr[i] = ex; cursor[i] = ex; }
}

__global__ void k_scatter(const int* __restrict__ srcv, const int* __restrict__ dstv,
                          int* __restrict__ cursor, int* __restrict__ col) {
  int e = blockIdx.x * blockDim.x + threadIdx.x;
  if (e < NE) {
    int d = dstv[e];
    int pos = atomicAdd(&cursor[d], 1);
    col[pos] = srcv[e];
  }
}

// ---------------- weight preconvert: fragment-order tiles ----------------
// per kstep (32 k): [col-group g(8)][kchunk q(4)][frow(16)][j(8)] ushorts = 4096
__device__ __forceinline__ size_t wtile_idx(int k, int c) {
  return (size_t)(k >> 5) * 4096 + ((((c >> 4) * 4 + ((k & 31) >> 3)) * 16 + (c & 15)) * 8 + (k & 7));
}

__global__ __launch_bounds__(256) void k_wconv0(const float* __restrict__ W0, const float* __restrict__ W1,
                                                const float* __restrict__ W2, const float* __restrict__ W3,
                                                ushort* __restrict__ wh, ushort* __restrict__ wl) {
  int id = blockIdx.x * 256 + threadIdx.x;           // 4*64*128 = 32768
  if (id >= 4 * 64 * 128) return;
  int mat = id >> 13, rem = id & 8191;
  int k = rem >> 7, c = rem & 127;
  const float* W = (mat == 0) ? W0 : (mat == 1) ? W1 : (mat == 2) ? W2 : W3;
  float v = W[k * 128 + c];
  ushort h = f2bf(v);
  ushort lo = f2bf(v - bf2f(h));
  size_t dst = (size_t)mat * 8192 + wtile_idx(k, c);
  wh[dst] = h; wl[dst] = lo;
}

__global__ __launch_bounds__(256) void k_wconvS(const float* __restrict__ Wq, const float* __restrict__ Wk,
                                                const float* __restrict__ Wv, const float* __restrict__ Ws,
                                                ushort* __restrict__ wh, ushort* __restrict__ wl) {
  int id = blockIdx.x * 256 + threadIdx.x;           // 5*4*128*128 = 327680
  if (id >= 5 * 4 * 16384) return;
  int lay = id / 65536, rem = id % 65536;
  int mat = rem >> 14, rem2 = rem & 16383;
  int k = rem2 >> 7, c = rem2 & 127;
  const float* W = (mat == 0) ? Wq : (mat == 1) ? Wk : (mat == 2) ? Wv : Ws;
  float v = W[(size_t)lay * 16384 + k * 128 + c];
  ushort h = f2bf(v);
  ushort lo = f2bf(v - bf2f(h));
  size_t dst = 32768 + ((size_t)lay * 4 + mat) * 16384 + wtile_idx(k, c);
  wh[dst] = h; wl[dst] = lo;
}

// ---------------- presplit: BN+ReLU + split-bf16, fragment-order tiled ----------------
// Xh layout: [kstep][row-block b(NB)][group g(8)][q(4)][frow(16)][j(8)] (4096 ushorts/block/kstep)
template <int K>
__global__ __launch_bounds__(256) void k_presplit(const float* __restrict__ Y, int use_bn,
                                                  const float* __restrict__ sums,
                                                  const float* __restrict__ sumsq,
                                                  const float* __restrict__ gvec,
                                                  const float* __restrict__ bvec,
                                                  ushort* __restrict__ Xh, ushort* __restrict__ Xl) {
  const int CP = K / 4;
  int idx = blockIdx.x * 256 + threadIdx.x;
  int row = idx / CP;
  int c4 = (idx % CP) * 4;
  if (row >= NN) return;
  float4 v = *reinterpret_cast<const float4*>(Y + (size_t)row * K + c4);
  if (use_bn) {
    const float invn = 1.f / (float)NN;
    float4 s4 = *reinterpret_cast<const float4*>(sums + c4);
    float4 q4 = *reinterpret_cast<const float4*>(sumsq + c4);
    float4 g4 = *reinterpret_cast<const float4*>(gvec + c4);
    float4 b4 = *reinterpret_cast<const float4*>(bvec + c4);
    float mu, var, sc, sh;
    mu = s4.x * invn; var = q4.x * invn - mu * mu; sc = g4.x * rsqrtf(var + 1e-5f); sh = b4.x - mu * sc;
    v.x = fmaxf(fmaf(v.x, sc, sh), 0.f);
    mu = s4.y * invn; var = q4.y * invn - mu * mu; sc = g4.y * rsqrtf(var + 1e-5f); sh = b4.y - mu * sc;
    v.y = fmaxf(fmaf(v.y, sc, sh), 0.f);
    mu = s4.z * invn; var = q4.z * invn - mu * mu; sc = g4.z * rsqrtf(var + 1e-5f); sh = b4.z - mu * sc;
    v.z = fmaxf(fmaf(v.z, sc, sh), 0.f);
    mu = s4.w * invn; var = q4.w * invn - mu * mu; sc = g4.w * rsqrtf(var + 1e-5f); sh = b4.w - mu * sc;
    v.w = fmaxf(fmaf(v.w, sc, sh), 0.f);
  }
  ushort h0 = f2bf(v.x), h1 = f2bf(v.y), h2 = f2bf(v.z), h3 = f2bf(v.w);
  ushort l0 = f2bf(v.x - bf2f(h0)), l1 = f2bf(v.y - bf2f(h1));
  ushort l2 = f2bf(v.z - bf2f(h2)), l3 = f2bf(v.w - bf2f(h3));
  int b = row >> 7, g = (row & 127) >> 4, frow = row & 15;
  int ks = c4 >> 5, qq = (c4 & 31) >> 3, j = c4 & 7;
  size_t base = ((size_t)ks * NB + b) * 4096 + (((g * 4 + qq) * 16) + frow) * 8 + j;
  *reinterpret_cast<uint2*>(Xh + base) =
      make_uint2((uint)h0 | ((uint)h1 << 16), (uint)h2 | ((uint)h3 << 16));
  *reinterpret_cast<uint2*>(Xl + base) =
      make_uint2((uint)l0 | ((uint)l1 << 16), (uint)l2 | ((uint)l3 << 16));
}

// ---------------- MFMA GEMM (pre-split A and B, global_load_lds staging) ----------------
// grid (NB, 4 mats), block 256 = 4 waves as 2x2 (64x64 per wave).
// mat 0 -> q (f32), mat 1 -> k half of kv (bf16, interleaved), mat 2 -> v half, mat 3 -> xs (f32)
template <int K>
__global__ __launch_bounds__(256, 2) void k_gemm(
    const ushort* __restrict__ Xh, const ushort* __restrict__ Xl,
    const ushort* __restrict__ Wth, const ushort* __restrict__ Wtl,
    const float* __restrict__ b0, const float* __restrict__ b1,
    const float* __restrict__ b2, const float* __restrict__ b3,
    float* __restrict__ Yq, ushort* __restrict__ kv, float* __restrict__ Yxs) {
  __shared__ __align__(16) ushort Ah[4096];
  __shared__ __align__(16) ushort Al[4096];
  __shared__ __align__(16) ushort Bh[4096];
  __shared__ __align__(16) ushort Bl[4096];
  int t = threadIdx.x;
  int lane = t & 63, w = t >> 6;
  int wr = w >> 1, wc = w & 1;
  int frow = lane & 15;
  int mat = blockIdx.y;
  const ushort* wh = Wth + (size_t)mat * (K * 128);
  const ushort* wl = Wtl + (size_t)mat * (K * 128);
  const float* bb = (mat == 0) ? b0 : (mat == 1) ? b1 : (mat == 2) ? b2 : b3;

  f32x4 acc[4][4];
#pragma unroll
  for (int i = 0; i < 4; ++i)
#pragma unroll
    for (int j = 0; j < 4; ++j)
#pragma unroll
      for (int r = 0; r < 4; ++r) acc[i][j][r] = 0.f;

  int wofs = w * 1024 + lane * 8;   // ushort offset within tile for staging
  for (int ks = 0; ks < K / 32; ++ks) {
    size_t abase = ((size_t)ks * NB + blockIdx.x) * 4096;
    const ushort* gAh = Xh + abase + wofs;
    const ushort* gAl = Xl + abase + wofs;
    const ushort* gBh = wh + ks * 4096 + wofs;
    const ushort* gBl = wl + ks * 4096 + wofs;
    gload16(gAh, &Ah[w * 1024]);
    gload16(gAh + 512, &Ah[w * 1024 + 512]);
    gload16(gAl, &Al[w * 1024]);
    gload16(gAl + 512, &Al[w * 1024 + 512]);
    gload16(gBh, &Bh[w * 1024]);
    gload16(gBh + 512, &Bh[w * 1024 + 512]);
    gload16(gBl, &Bl[w * 1024]);
    gload16(gBl + 512, &Bl[w * 1024 + 512]);
    __syncthreads();
    s16x8 ah[4], al[4], bh[4], bl[4];
#pragma unroll
    for (int g = 0; g < 4; ++g) {
      ah[g] = *reinterpret_cast<const s16x8*>(&Ah[(wr * 4 + g) * 512 + lane * 8]);
      al[g] = *reinterpret_cast<const s16x8*>(&Al[(wr * 4 + g) * 512 + lane * 8]);
      bh[g] = *reinterpret_cast<const s16x8*>(&Bh[(wc * 4 + g) * 512 + lane * 8]);
      bl[g] = *reinterpret_cast<const s16x8*>(&Bl[(wc * 4 + g) * 512 + lane * 8]);
    }
#pragma unroll
    for (int rg = 0; rg < 4; ++rg)
#pragma unroll
      for (int cg = 0; cg < 4; ++cg) {
        acc[rg][cg] = __builtin_amdgcn_mfma_f32_16x16x32_bf16(ah[rg], bh[cg], acc[rg][cg], 0, 0, 0);
        acc[rg][cg] = __builtin_amdgcn_mfma_f32_16x16x32_bf16(al[rg], bh[cg], acc[rg][cg], 0, 0, 0);
        acc[rg][cg] = __builtin_amdgcn_mfma_f32_16x16x32_bf16(ah[rg], bl[cg], acc[rg][cg], 0, 0, 0);
      }
    __syncthreads();
  }
  // epilogue: D row=(lane>>4)*4+r, col=lane&15 within 16x16 frag
  int r0 = blockIdx.x * 128;
  int qq = (lane >> 4) << 2;
#pragma unroll
  for (int rg = 0; rg < 4; ++rg) {
#pragma unroll
    for (int cg = 0; cg < 4; ++cg) {
      int colg = wc * 64 + cg * 16 + frow;
      float bv = bb[colg];
#pragma unroll
      for (int r = 0; r < 4; ++r) {
        int row = r0 + wr * 64 + rg * 16 + qq + r;
        if (row >= NN) continue;
        float val = acc[rg][cg][r] + bv;
        if (mat == 0)      Yq [(size_t)row * FHH + colg] = val;
        else if (mat == 3) Yxs[(size_t)row * FHH + colg] = val;
        else {
          int pos = (colg >> 1) * 4 + ((mat == 2) ? 2 : 0) + (colg & 1);
          kv[(size_t)row * 256 + pos] = f2bf(val);
        }
      }
    }
  }
}

// ---------------- node-centric online-softmax aggregate, interleaved bf16 kv ----------------
// 64 lanes per node, 2 features/lane; 2 nodes per 128-thread block.
__global__ __launch_bounds__(128) void k_agg(const float* __restrict__ q,
                                             const ushort* __restrict__ kv,
                                             const float* __restrict__ xs,
                                             const int* __restrict__ row_ptr,
                                             const int* __restrict__ col,
                                             float* __restrict__ y) {
  int n = blockIdx.x * 2 + (threadIdx.x >> 6);
  int t = threadIdx.x & 63;
  float2 qf = *reinterpret_cast<const float2*>(q + (size_t)n * FHH + 2 * t);
  const uint2* kvp = reinterpret_cast<const uint2*>(kv);
  int e0 = row_ptr[n], e1 = row_ptr[n + 1];
  float m = -INFINITY, sum = 0.f, a0 = 0.f, a1 = 0.f;
  int i = e0;
  for (; i + 4 <= e1; i += 4) {
    int s0 = col[i], s1 = col[i + 1], s2 = col[i + 2], s3 = col[i + 3];
    uint2 d0 = kvp[((size_t)s0 << 6) + t];
    uint2 d1 = kvp[((size_t)s1 << 6) + t];
    uint2 d2 = kvp[((size_t)s2 << 6) + t];
    uint2 d3 = kvp[((size_t)s3 << 6) + t];
    float p0 = fmaf(qf.x, bfl(d0.x), qf.y * bfh(d0.x));
    float p1 = fmaf(qf.x, bfl(d1.x), qf.y * bfh(d1.x));
    float p2 = fmaf(qf.x, bfl(d2.x), qf.y * bfh(d2.x));
    float p3 = fmaf(qf.x, bfl(d3.x), qf.y * bfh(d3.x));
    p0 += __shfl_xor(p0, 1, 8); p1 += __shfl_xor(p1, 1, 8);
    p2 += __shfl_xor(p2, 1, 8); p3 += __shfl_xor(p3, 1, 8);
    p0 += __shfl_xor(p0, 2, 8); p1 += __shfl_xor(p1, 2, 8);
    p2 += __shfl_xor(p2, 2, 8); p3 += __shfl_xor(p3, 2, 8);
    p0 += __shfl_xor(p0, 4, 8); p1 += __shfl_xor(p1, 4, 8);
    p2 += __shfl_xor(p2, 4, 8); p3 += __shfl_xor(p3, 4, 8);
    float sc0 = p0 * 0.25f, sc1 = p1 * 0.25f, sc2 = p2 * 0.25f, sc3 = p3 * 0.25f;
    float nm = fmaxf(m, fmaxf(fmaxf(sc0, sc1), fmaxf(sc2, sc3)));
    float r = __expf(m - nm);
    float w0 = __expf(sc0 - nm), w1 = __expf(sc1 - nm);
    float w2 = __expf(sc2 - nm), w3 = __expf(sc3 - nm);
    sum = fmaf(sum, r, (w0 + w1) + (w2 + w3));
    a0 = fmaf(a0, r, fmaf(w0, bfl(d0.y), fmaf(w1, bfl(d1.y), fmaf(w2, bfl(d2.y), w3 * bfl(d3.y)))));
    a1 = fmaf(a1, r, fmaf(w0, bfh(d0.y), fmaf(w1, bfh(d1.y), fmaf(w2, bfh(d2.y), w3 * bfh(d3.y)))));
    m = nm;
  }
  for (; i < e1; ++i) {
    int s0 = col[i];
    uint2 d0 = kvp[((size_t)s0 << 6) + t];
    float p0 = fmaf(qf.x, bfl(d0.x), qf.y * bfh(d0.x));
    p0 += __shfl_xor(p0, 1, 8);
    p0 += __shfl_xor(p0, 2, 8);
    p0 += __shfl_xor(p0, 4, 8);
    float sc0 = p0 * 0.25f;
    float nm = fmaxf(m, sc0);
    float r = __expf(m - nm);
    float w0 = __expf(sc0 - nm);
    sum = fmaf(sum, r, w0);
    a0 = fmaf(a0, r, w0 * bfl(d0.y));
    a1 = fmaf(a1, r, w0 * bfh(d0.y));
    m = nm;
  }
  float inv = 1.f / fmaxf(sum, 1e-16f);
  float2 xv = *reinterpret_cast<const float2*>(xs + (size_t)n * FHH + 2 * t);
  float2 ov;
  ov.x = fmaf(a0, inv, xv.x);
  ov.y = fmaf(a1, inv, xv.y);
  *reinterpret_cast<float2*>(y + (size_t)n * FHH + 2 * t) = ov;
}

// ---------------- BN statistics ----------------
__global__ __launch_bounds__(256) void k_bnstats(const float* __restrict__ y,
                                                 float* __restrict__ sums,
                                                 float* __restrict__ sumsq) {
  __shared__ float s1[256], s2[256];
  int f = threadIdx.x & 127;
  int half = threadIdx.x >> 7;
  float a = 0.f, b = 0.f;
  for (int r = blockIdx.x * 2 + half; r < NN; r += 512) {
    float val = y[(size_t)r * FHH + f];
    a += val;
    b += val * val;
  }
  s1[threadIdx.x] = a;
  s2[threadIdx.x] = b;
  __syncthreads();
  if (half == 0) {
    a += s1[threadIdx.x + 128];
    b += s2[threadIdx.x + 128];
    atomicAdd(&sums[f], a);
    atomicAdd(&sumsq[f], b);
  }
}

// ---------------- per-graph mean pooling of act(y), 4-way row split ----------------
__global__ __launch_bounds__(128) void k_pool(const float* __restrict__ y,
                                              const float* __restrict__ sums,
                                              const float* __restrict__ sumsq,
                                              const float* __restrict__ gvec,
                                              const float* __restrict__ bvec,
                                              const int* __restrict__ gstart,
                                              float* __restrict__ out, int layer) {
  int g = blockIdx.x;
  int part = blockIdx.y;
  int f = threadIdx.x;
  const float invn = 1.f / (float)NN;
  float mu = sums[f] * invn;
  float var = sumsq[f] * invn - mu * mu;
  float sc = gvec[f] * rsqrtf(var + 1e-5f);
  float sh = bvec[f] - mu * sc;
  int r0 = gstart[g], r1 = gstart[g + 1];
  int len = r1 - r0;
  int q0 = r0 + (len * part) / 4;
  int q1 = r0 + (len * (part + 1)) / 4;
  float s = 0.f;
  for (int r = q0; r < q1; ++r) s += fmaxf(fmaf(y[(size_t)r * FHH + f], sc, sh), 0.f);
  float p = s / (float)(len > 0 ? len : 1);
  if (layer < 5) {
    atomicAdd(&out[(size_t)g * 1024 + layer * FHH + f], p);
  } else {
    atomicAdd(&out[(size_t)g * 1024 + 5 * FHH + f], p);
    atomicAdd(&out[(size_t)g * 1024 + 6 * FHH + f], p);
    atomicAdd(&out[(size_t)g * 1024 + 7 * FHH + f], p);
  }
}

extern "C" void kernel_launch(void* const* d_in, const int* in_sizes, int n_in,
                              void* d_out, int out_size, void* d_ws, size_t ws_size,
                              hipStream_t stream) {
  (void)in_sizes; (void)n_in; (void)ws_size;
  const float* x    = (const float*)d_in[0];
  const int*   ei   = (const int*)d_in[1];
  const int*   bvec = (const int*)d_in[2];
  const float* Wq0  = (const float*)d_in[3];
  const float* bq0  = (const float*)d_in[4];
  const float* Wk0  = (const float*)d_in[5];
  const float* bk0  = (const float*)d_in[6];
  const float* Wv0  = (const float*)d_in[7];
  const float* bv0  = (const float*)d_in[8];
  const float* Ws0  = (const float*)d_in[9];
  const float* bs0  = (const float*)d_in[10];
  const float* WqS  = (const float*)d_in[11];
  const float* bqS  = (const float*)d_in[12];
  const float* WkS  = (const float*)d_in[13];
  const float* bkS  = (const float*)d_in[14];
  const float* WvS  = (const float*)d_in[15];
  const float* bvS  = (const float*)d_in[16];
  const float* WsS  = (const float*)d_in[17];
  const float* bsS  = (const float*)d_in[18];
  const float* gamma = (const float*)d_in[19];
  const float* beta  = (const float*)d_in[20];
  float* out = (float*)d_out;

  char* ws = (char*)d_ws;
  size_t off = 0;
  auto alloc = [&](size_t bytes) {
    void* p = ws + off;
    off = (off + bytes + 255) & ~(size_t)255;
    return p;
  };
  float* q    = (float*)alloc((size_t)NN * FHH * 4);
  float* xs   = (float*)alloc((size_t)NN * FHH * 4);
  float* y    = (float*)alloc((size_t)NN * FHH * 4);
  ushort* kv  = (ushort*)alloc((size_t)NN * 256 * 2);
  ushort* Xh  = (ushort*)alloc((size_t)4 * NB * 4096 * 2 + 8192);
  ushort* Xl  = (ushort*)alloc((size_t)4 * NB * 4096 * 2 + 8192);
  int* col     = (int*)alloc((size_t)NE * 4);
  int* row_ptr = (int*)alloc((size_t)(NN + 1) * 4);
  int* cursor  = (int*)alloc((size_t)NN * 4);
  int* deg     = (int*)alloc((size_t)NN * 4);
  int* part    = (int*)alloc((size_t)NCH * 4);
  int* gstart  = (int*)alloc((size_t)(NG + 1) * 4);
  float* bstat = (float*)alloc((size_t)NL * 2 * FHH * 4);   // [layer][{sum,sumsq}][128]
  ushort* wsh = (ushort*)alloc((size_t)360448 * 2);
  ushort* wsl = (ushort*)alloc((size_t)360448 * 2);

  const int* srcv = ei;
  const int* dstv = ei + NE;

  hipMemsetAsync(out, 0, (size_t)out_size * 4, stream);
  hipMemsetAsync(deg, 0, (size_t)NN * 4, stream);
  hipMemsetAsync(bstat, 0, (size_t)NL * 2 * FHH * 4, stream);
  k_gstart<<<5, 64, 0, stream>>>(bvec, gstart);
  k_deg<<<(NE + 255) / 256, 256, 0, stream>>>(dstv, deg);
  k_scanA<<<NCH, 256, 0, stream>>>(deg, part);
  k_scanB<<<1, 64, 0, stream>>>(part, row_ptr);
  k_scanC<<<NCH, 1024, 0, stream>>>(deg, part, row_ptr, cursor);
  k_scatter<<<(NE + 255) / 256, 256, 0, stream>>>(srcv, dstv, cursor, col);
  k_wconv0<<<128, 256, 0, stream>>>(Wq0, Wk0, Wv0, Ws0, wsh, wsl);
  k_wconvS<<<1280, 256, 0, stream>>>(WqS, WkS, WvS, WsS, wsh, wsl);
  k_presplit<64><<<(NN * 16 + 255) / 256, 256, 0, stream>>>(x, 0, nullptr, nullptr,
                                                            nullptr, nullptr, Xh, Xl);

  for (int l = 0; l < NL; ++l) {
    const ushort* WthL = wsh + ((l == 0) ? 0 : (size_t)32768 + (size_t)(l - 1) * 65536);
    const ushort* WtlL = wsl + ((l == 0) ? 0 : (size_t)32768 + (size_t)(l - 1) * 65536);
    const float *bq_, *bk_, *bv_, *bs_;
    if (l == 0) { bq_ = bq0; bk_ = bk0; bv_ = bv0; bs_ = bs0; }
    else {
      size_t bo = (size_t)(l - 1) * FHH;
      bq_ = bqS + bo; bk_ = bkS + bo; bv_ = bvS + bo; bs_ = bsS + bo;
    }
    dim3 gg(NB, 4);
    if (l == 0)
      k_gemm<64><<<gg, 256, 0, stream>>>(Xh, Xl, WthL, WtlL, bq_, bk_, bv_, bs_, q, kv, xs);
    else
      k_gemm<128><<<gg, 256, 0, stream>>>(Xh, Xl, WthL, WtlL, bq_, bk_, bv_, bs_, q, kv, xs);
    k_agg<<<NN / 2, 128, 0, stream>>>(q, kv, xs, row_ptr, col, y);
    float* lsum = bstat + (size_t)l * 2 * FHH;
    float* lsqs = lsum + FHH;
    k_bnstats<<<256, 256, 0, stream>>>(y, lsum, lsqs);
    dim3 pg2(NG, 4);
    k_pool<<<pg2, FHH, 0, stream>>>(y, lsum, lsqs, gamma + (size_t)l * FHH,
                                    beta + (size_t)l * FHH, gstart, out, l);
    if (l + 1 < NL)
      k_presplit<128><<<(NN * 32 + 255) / 256, 256, 0, stream>>>(
          y, 1, lsum, lsqs, gamma + (size_t)l * FHH, beta + (size_t)l * FHH, Xh, Xl);
  }
}

// Round 5
// 1019.359 us; speedup vs baseline: 2.0247x; 1.0974x over previous
//
#include <hip/hip_runtime.h>
#include <hip/hip_bf16.h>
#include <math.h>

#define NN 50000
#define NE 800000
#define NG 256
#define FHH 128
#define NL 6
#define NCH 49    // ceil(50000/1024)
#define NB 391    // ceil(50000/128) row-blocks

typedef __attribute__((ext_vector_type(8))) short s16x8;
typedef __attribute__((ext_vector_type(4))) float f32x4;

#define QSCALE 0.36067376022224085f   // 0.25 * log2(e)

__device__ __forceinline__ ushort f2bf(float x) {
  uint u = __float_as_uint(x);
  u += 0x7fffu + ((u >> 16) & 1u);
  return (ushort)(u >> 16);
}
__device__ __forceinline__ float bf2f(ushort h) {
  return __uint_as_float(((uint)h) << 16);
}
__device__ __forceinline__ float bfl(uint u) { return __uint_as_float(u << 16); }
__device__ __forceinline__ float bfh(uint u) { return __uint_as_float(u & 0xffff0000u); }

__device__ __forceinline__ void gload16(const ushort* g, ushort* l) {
  __builtin_amdgcn_global_load_lds(
      (const __attribute__((address_space(1))) uint*)(const void*)g,
      (__attribute__((address_space(3))) uint*)(void*)l, 16, 0, 0);
}

// ---------------- graph-boundary search (batch_vec sorted) ----------------
__global__ void k_gstart(const int* __restrict__ bv, int* __restrict__ gstart) {
  int g = blockIdx.x * blockDim.x + threadIdx.x;
  if (g > NG) return;
  int lo = 0, hi = NN;
  while (lo < hi) { int mid = (lo + hi) >> 1; if (bv[mid] < g) lo = mid + 1; else hi = mid; }
  gstart[g] = lo;
}

// ---------------- CSR build (by dst) ----------------
__global__ void k_deg(const int* __restrict__ dstv, int* __restrict__ deg) {
  int e = blockIdx.x * blockDim.x + threadIdx.x;
  if (e < NE) atomicAdd(&deg[dstv[e]], 1);
}

__global__ __launch_bounds__(256) void k_scanA(const int* __restrict__ deg, int* __restrict__ part) {
  int b = blockIdx.x, t = threadIdx.x;
  int s = 0;
  for (int j = t; j < 1024; j += 256) { int i = b * 1024 + j; if (i < NN) s += deg[i]; }
  __shared__ int sh[4];
  for (int o = 32; o; o >>= 1) s += __shfl_down(s, o, 64);
  if ((t & 63) == 0) sh[t >> 6] = s;
  __syncthreads();
  if (t == 0) part[b] = sh[0] + sh[1] + sh[2] + sh[3];
}

__global__ void k_scanB(int* __restrict__ part, int* __restrict__ row_ptr) {
  if (threadIdx.x == 0 && blockIdx.x == 0) {
    int run = 0;
    for (int i = 0; i < NCH; ++i) { int v = part[i]; part[i] = run; run += v; }
    row_ptr[NN] = run;
  }
}

__global__ __launch_bounds__(1024) void k_scanC(const int* __restrict__ deg, const int* __restrict__ part,
                                                int* __restrict__ row_ptr, int* __restrict__ cursor) {
  __shared__ int buf[1024];
  int b = blockIdx.x, t = threadIdx.x;
  int i = b * 1024 + t;
  int v = (i < NN) ? deg[i] : 0;
  buf[t] = v;
  __syncthreads();
  for (int off = 1; off < 1024; off <<= 1) {
    int add = (t >= off) ? buf[t - off] : 0;
    __syncthreads();
    buf[t] += add;
    __syncthreads();
  }
  if (i < NN) { int ex = part[b] + buf[t] - v; row_ptr[i] = ex; cursor[i] = ex; }
}

// col stores BYTE offsets of kv rows (src * 512)
__global__ void k_scatter(const int* __restrict__ srcv, const int* __restrict__ dstv,
                          int* __restrict__ cursor, uint* __restrict__ colb) {
  int e = blockIdx.x * blockDim.x + threadIdx.x;
  if (e < NE) {
    int d = dstv[e];
    int pos = atomicAdd(&cursor[d], 1);
    colb[pos] = ((uint)srcv[e]) << 9;
  }
}

// ---------------- weight preconvert: fragment-order tiles ----------------
__device__ __forceinline__ size_t wtile_idx(int k, int c) {
  return (size_t)(k >> 5) * 4096 + ((((c >> 4) * 4 + ((k & 31) >> 3)) * 16 + (c & 15)) * 8 + (k & 7));
}

__global__ __launch_bounds__(256) void k_wconv0(const float* __restrict__ W0, const float* __restrict__ W1,
                                                const float* __restrict__ W2, const float* __restrict__ W3,
                                                ushort* __restrict__ wh, ushort* __restrict__ wl) {
  int id = blockIdx.x * 256 + threadIdx.x;           // 4*64*128 = 32768
  if (id >= 4 * 64 * 128) return;
  int mat = id >> 13, rem = id & 8191;
  int k = rem >> 7, c = rem & 127;
  const float* W = (mat == 0) ? W0 : (mat == 1) ? W1 : (mat == 2) ? W2 : W3;
  float v = W[k * 128 + c];
  ushort h = f2bf(v);
  ushort lo = f2bf(v - bf2f(h));
  size_t dst = (size_t)mat * 8192 + wtile_idx(k, c);
  wh[dst] = h; wl[dst] = lo;
}

__global__ __launch_bounds__(256) void k_wconvS(const float* __restrict__ Wq, const float* __restrict__ Wk,
                                                const float* __restrict__ Wv, const float* __restrict__ Ws,
                                                ushort* __restrict__ wh, ushort* __restrict__ wl) {
  int id = blockIdx.x * 256 + threadIdx.x;           // 5*4*128*128 = 327680
  if (id >= 5 * 4 * 16384) return;
  int lay = id / 65536, rem = id % 65536;
  int mat = rem >> 14, rem2 = rem & 16383;
  int k = rem2 >> 7, c = rem2 & 127;
  const float* W = (mat == 0) ? Wq : (mat == 1) ? Wk : (mat == 2) ? Wv : Ws;
  float v = W[(size_t)lay * 16384 + k * 128 + c];
  ushort h = f2bf(v);
  ushort lo = f2bf(v - bf2f(h));
  size_t dst = 32768 + ((size_t)lay * 4 + mat) * 16384 + wtile_idx(k, c);
  wh[dst] = h; wl[dst] = lo;
}

// ---------------- presplit (layer-0 input only): split-bf16, fragment-order tiled ----------------
template <int K>
__global__ __launch_bounds__(256) void k_presplit(const float* __restrict__ Y,
                                                  ushort* __restrict__ Xh, ushort* __restrict__ Xl) {
  const int CP = K / 4;
  int idx = blockIdx.x * 256 + threadIdx.x;
  int row = idx / CP;
  int c4 = (idx % CP) * 4;
  if (row >= NN) return;
  float4 v = *reinterpret_cast<const float4*>(Y + (size_t)row * K + c4);
  ushort h0 = f2bf(v.x), h1 = f2bf(v.y), h2 = f2bf(v.z), h3 = f2bf(v.w);
  ushort l0 = f2bf(v.x - bf2f(h0)), l1 = f2bf(v.y - bf2f(h1));
  ushort l2 = f2bf(v.z - bf2f(h2)), l3 = f2bf(v.w - bf2f(h3));
  int b = row >> 7, g = (row & 127) >> 4, frow = row & 15;
  int ks = c4 >> 5, qq = (c4 & 31) >> 3, j = c4 & 7;
  size_t base = ((size_t)ks * NB + b) * 4096 + (((g * 4 + qq) * 16) + frow) * 8 + j;
  *reinterpret_cast<uint2*>(Xh + base) =
      make_uint2((uint)h0 | ((uint)h1 << 16), (uint)h2 | ((uint)h3 << 16));
  *reinterpret_cast<uint2*>(Xl + base) =
      make_uint2((uint)l0 | ((uint)l1 << 16), (uint)l2 | ((uint)l3 << 16));
}

// ---------------- MFMA GEMM (pre-split A and B, global_load_lds staging) ----------------
// mat 0 -> q (bf16, pre-scaled by 0.25*log2e), mat 1 -> k half of kv, mat 2 -> v half, mat 3 -> xs (f32)
template <int K>
__global__ __launch_bounds__(256, 2) void k_gemm(
    const ushort* __restrict__ Xh, const ushort* __restrict__ Xl,
    const ushort* __restrict__ Wth, const ushort* __restrict__ Wtl,
    const float* __restrict__ b0, const float* __restrict__ b1,
    const float* __restrict__ b2, const float* __restrict__ b3,
    ushort* __restrict__ qbf, ushort* __restrict__ kv, float* __restrict__ Yxs) {
  __shared__ __align__(16) ushort Ah[4096];
  __shared__ __align__(16) ushort Al[4096];
  __shared__ __align__(16) ushort Bh[4096];
  __shared__ __align__(16) ushort Bl[4096];
  int t = threadIdx.x;
  int lane = t & 63, w = t >> 6;
  int wr = w >> 1, wc = w & 1;
  int frow = lane & 15;
  int mat = blockIdx.y;
  const ushort* wh = Wth + (size_t)mat * (K * 128);
  const ushort* wl = Wtl + (size_t)mat * (K * 128);
  const float* bb = (mat == 0) ? b0 : (mat == 1) ? b1 : (mat == 2) ? b2 : b3;

  f32x4 acc[4][4];
#pragma unroll
  for (int i = 0; i < 4; ++i)
#pragma unroll
    for (int j = 0; j < 4; ++j)
#pragma unroll
      for (int r = 0; r < 4; ++r) acc[i][j][r] = 0.f;

  int wofs = w * 1024 + lane * 8;
  for (int ks = 0; ks < K / 32; ++ks) {
    size_t abase = ((size_t)ks * NB + blockIdx.x) * 4096;
    const ushort* gAh = Xh + abase + wofs;
    const ushort* gAl = Xl + abase + wofs;
    const ushort* gBh = wh + ks * 4096 + wofs;
    const ushort* gBl = wl + ks * 4096 + wofs;
    gload16(gAh, &Ah[w * 1024]);
    gload16(gAh + 512, &Ah[w * 1024 + 512]);
    gload16(gAl, &Al[w * 1024]);
    gload16(gAl + 512, &Al[w * 1024 + 512]);
    gload16(gBh, &Bh[w * 1024]);
    gload16(gBh + 512, &Bh[w * 1024 + 512]);
    gload16(gBl, &Bl[w * 1024]);
    gload16(gBl + 512, &Bl[w * 1024 + 512]);
    __syncthreads();
    s16x8 ah[4], al[4], bh[4], bl[4];
#pragma unroll
    for (int g = 0; g < 4; ++g) {
      ah[g] = *reinterpret_cast<const s16x8*>(&Ah[(wr * 4 + g) * 512 + lane * 8]);
      al[g] = *reinterpret_cast<const s16x8*>(&Al[(wr * 4 + g) * 512 + lane * 8]);
      bh[g] = *reinterpret_cast<const s16x8*>(&Bh[(wc * 4 + g) * 512 + lane * 8]);
      bl[g] = *reinterpret_cast<const s16x8*>(&Bl[(wc * 4 + g) * 512 + lane * 8]);
    }
#pragma unroll
    for (int rg = 0; rg < 4; ++rg)
#pragma unroll
      for (int cg = 0; cg < 4; ++cg) {
        acc[rg][cg] = __builtin_amdgcn_mfma_f32_16x16x32_bf16(ah[rg], bh[cg], acc[rg][cg], 0, 0, 0);
        acc[rg][cg] = __builtin_amdgcn_mfma_f32_16x16x32_bf16(al[rg], bh[cg], acc[rg][cg], 0, 0, 0);
        acc[rg][cg] = __builtin_amdgcn_mfma_f32_16x16x32_bf16(ah[rg], bl[cg], acc[rg][cg], 0, 0, 0);
      }
    __syncthreads();
  }
  int r0 = blockIdx.x * 128;
  int qq = (lane >> 4) << 2;
#pragma unroll
  for (int rg = 0; rg < 4; ++rg) {
#pragma unroll
    for (int cg = 0; cg < 4; ++cg) {
      int colg = wc * 64 + cg * 16 + frow;
      float bv = bb[colg];
#pragma unroll
      for (int r = 0; r < 4; ++r) {
        int row = r0 + wr * 64 + rg * 16 + qq + r;
        if (row >= NN) continue;
        float val = acc[rg][cg][r] + bv;
        if (mat == 0)      qbf[(size_t)row * FHH + colg] = f2bf(val * QSCALE);
        else if (mat == 3) Yxs[(size_t)row * FHH + colg] = val;
        else {
          int pos = (colg >> 1) * 4 + ((mat == 2) ? 2 : 0) + (colg & 1);
          kv[(size_t)row * 256 + pos] = f2bf(val);
        }
      }
    }
  }
}

// ---------------- node-centric softmax aggregate (no-max, exp2, bf16 q, byte-offset col) ----------------
// 64 lanes per node, 2 features/lane; 4 nodes per 256-thread block.
__global__ __launch_bounds__(256) void k_agg(const uint* __restrict__ qb,
                                             const ushort* __restrict__ kv,
                                             const float* __restrict__ xs,
                                             const int* __restrict__ row_ptr,
                                             const uint* __restrict__ colb,
                                             float* __restrict__ y) {
  int n = blockIdx.x * 4 + (threadIdx.x >> 6);
  int t = threadIdx.x & 63;
  uint qp = qb[(n << 6) + t];
  float qx = bfl(qp), qy = bfh(qp);     // q pre-scaled by 0.25*log2e
  const char* kvb = (const char*)kv;
  uint tof = (uint)t * 8u;
  int e0 = row_ptr[n], e1 = row_ptr[n + 1];
  float sum = 0.f, a0 = 0.f, a1 = 0.f;
  int i = e0;
  for (; i + 4 <= e1; i += 4) {
    uint o0 = colb[i] + tof, o1 = colb[i + 1] + tof;
    uint o2 = colb[i + 2] + tof, o3 = colb[i + 3] + tof;
    uint2 d0 = *(const uint2*)(kvb + o0);
    uint2 d1 = *(const uint2*)(kvb + o1);
    uint2 d2 = *(const uint2*)(kvb + o2);
    uint2 d3 = *(const uint2*)(kvb + o3);
    float p0 = fmaf(qx, bfl(d0.x), qy * bfh(d0.x));
    float p1 = fmaf(qx, bfl(d1.x), qy * bfh(d1.x));
    float p2 = fmaf(qx, bfl(d2.x), qy * bfh(d2.x));
    float p3 = fmaf(qx, bfl(d3.x), qy * bfh(d3.x));
    p0 += __shfl_xor(p0, 1, 8); p1 += __shfl_xor(p1, 1, 8);
    p2 += __shfl_xor(p2, 1, 8); p3 += __shfl_xor(p3, 1, 8);
    p0 += __shfl_xor(p0, 2, 8); p1 += __shfl_xor(p1, 2, 8);
    p2 += __shfl_xor(p2, 2, 8); p3 += __shfl_xor(p3, 2, 8);
    p0 += __shfl_xor(p0, 4, 8); p1 += __shfl_xor(p1, 4, 8);
    p2 += __shfl_xor(p2, 4, 8); p3 += __shfl_xor(p3, 4, 8);
    float w0 = exp2f(fminf(p0, 110.f));
    float w1 = exp2f(fminf(p1, 110.f));
    float w2 = exp2f(fminf(p2, 110.f));
    float w3 = exp2f(fminf(p3, 110.f));
    sum += (w0 + w1) + (w2 + w3);
    a0 = fmaf(w0, bfl(d0.y), fmaf(w1, bfl(d1.y), fmaf(w2, bfl(d2.y), fmaf(w3, bfl(d3.y), a0))));
    a1 = fmaf(w0, bfh(d0.y), fmaf(w1, bfh(d1.y), fmaf(w2, bfh(d2.y), fmaf(w3, bfh(d3.y), a1))));
  }
  for (; i < e1; ++i) {
    uint o0 = colb[i] + tof;
    uint2 d0 = *(const uint2*)(kvb + o0);
    float p0 = fmaf(qx, bfl(d0.x), qy * bfh(d0.x));
    p0 += __shfl_xor(p0, 1, 8);
    p0 += __shfl_xor(p0, 2, 8);
    p0 += __shfl_xor(p0, 4, 8);
    float w0 = exp2f(fminf(p0, 110.f));
    sum += w0;
    a0 = fmaf(w0, bfl(d0.y), a0);
    a1 = fmaf(w0, bfh(d0.y), a1);
  }
  float inv = 1.f / fmaxf(sum, 1e-16f);
  float2 xv = *reinterpret_cast<const float2*>(xs + ((size_t)n << 7) + 2 * t);
  float2 ov;
  ov.x = fmaf(a0, inv, xv.x);
  ov.y = fmaf(a1, inv, xv.y);
  *reinterpret_cast<float2*>(y + ((size_t)n << 7) + 2 * t) = ov;
}

// ---------------- BN statistics ----------------
__global__ __launch_bounds__(256) void k_bnstats(const float* __restrict__ y,
                                                 float* __restrict__ sums,
                                                 float* __restrict__ sumsq) {
  __shared__ float s1[256], s2[256];
  int f = threadIdx.x & 127;
  int half = threadIdx.x >> 7;
  float a = 0.f, b = 0.f;
  for (int r = blockIdx.x * 2 + half; r < NN; r += 512) {
    float val = y[(size_t)r * FHH + f];
    a += val;
    b += val * val;
  }
  s1[threadIdx.x] = a;
  s2[threadIdx.x] = b;
  __syncthreads();
  if (half == 0) {
    a += s1[threadIdx.x + 128];
    b += s2[threadIdx.x + 128];
    atomicAdd(&sums[f], a);
    atomicAdd(&sumsq[f], b);
  }
}

// ---------------- fused post: BN+ReLU once -> (pool atomic means) + (split-bf16 fragment write) ----------
// grid 6250, block 256: 8 rows x 128 cols per block; thread = (row_local = t>>5, c4 = (t&31)*4)
template <int WRITE_X>
__global__ __launch_bounds__(256) void k_post(const float* __restrict__ y,
                                              const float* __restrict__ sums,
                                              const float* __restrict__ sumsq,
                                              const float* __restrict__ gvec,
                                              const float* __restrict__ bvec_,
                                              const int* __restrict__ bv,
                                              const int* __restrict__ gstart,
                                              float* __restrict__ out, int layer,
                                              ushort* __restrict__ Xh, ushort* __restrict__ Xl) {
  __shared__ float acts[8][128];
  __shared__ int sg[8];
  __shared__ float ssc[128], ssh[128];
  int b = blockIdx.x, t = threadIdx.x;
  if (t < 128) {
    const float invn = 1.f / (float)NN;
    float mu = sums[t] * invn;
    float var = sumsq[t] * invn - mu * mu;
    float sc = gvec[t] * rsqrtf(var + 1e-5f);
    ssc[t] = sc;
    ssh[t] = bvec_[t] - mu * sc;
  }
  if (t < 8) sg[t] = (b * 8 + t < NN) ? bv[b * 8 + t] : -1;
  __syncthreads();
  int row = b * 8 + (t >> 5);
  int c4 = (t & 31) * 4;
  bool ok = row < NN;
  float4 a = make_float4(0.f, 0.f, 0.f, 0.f);
  if (ok) {
    float4 v = *reinterpret_cast<const float4*>(y + (size_t)row * FHH + c4);
    a.x = fmaxf(fmaf(v.x, ssc[c4 + 0], ssh[c4 + 0]), 0.f);
    a.y = fmaxf(fmaf(v.y, ssc[c4 + 1], ssh[c4 + 1]), 0.f);
    a.z = fmaxf(fmaf(v.z, ssc[c4 + 2], ssh[c4 + 2]), 0.f);
    a.w = fmaxf(fmaf(v.w, ssc[c4 + 3], ssh[c4 + 3]), 0.f);
  }
  *reinterpret_cast<float4*>(&acts[t >> 5][c4]) = a;
  if (WRITE_X && ok) {
    ushort h0 = f2bf(a.x), h1 = f2bf(a.y), h2 = f2bf(a.z), h3 = f2bf(a.w);
    ushort l0 = f2bf(a.x - bf2f(h0)), l1 = f2bf(a.y - bf2f(h1));
    ushort l2 = f2bf(a.z - bf2f(h2)), l3 = f2bf(a.w - bf2f(h3));
    int bb = row >> 7, g = (row & 127) >> 4, frow = row & 15;
    int ks = c4 >> 5, qq = (c4 & 31) >> 3, j = c4 & 7;
    size_t base = ((size_t)ks * NB + bb) * 4096 + (((g * 4 + qq) * 16) + frow) * 8 + j;
    *reinterpret_cast<uint2*>(Xh + base) =
        make_uint2((uint)h0 | ((uint)h1 << 16), (uint)h2 | ((uint)h3 << 16));
    *reinterpret_cast<uint2*>(Xl + base) =
        make_uint2((uint)l0 | ((uint)l1 << 16), (uint)l2 | ((uint)l3 << 16));
  }
  __syncthreads();
  if (t < 128) {
    float racc = 0.f;
    int cg = sg[0];
    for (int r = 0; r < 8; ++r) {
      int g = sg[r];
      if (g != cg) {
        if (cg >= 0) {
          float p = racc / (float)(gstart[cg + 1] - gstart[cg]);
          if (layer < 5) atomicAdd(&out[(size_t)cg * 1024 + layer * FHH + t], p);
          else {
            atomicAdd(&out[(size_t)cg * 1024 + 5 * FHH + t], p);
            atomicAdd(&out[(size_t)cg * 1024 + 6 * FHH + t], p);
            atomicAdd(&out[(size_t)cg * 1024 + 7 * FHH + t], p);
          }
        }
        racc = 0.f;
        cg = g;
      }
      racc += acts[r][t];
    }
    if (cg >= 0) {
      float p = racc / (float)(gstart[cg + 1] - gstart[cg]);
      if (layer < 5) atomicAdd(&out[(size_t)cg * 1024 + layer * FHH + t], p);
      else {
        atomicAdd(&out[(size_t)cg * 1024 + 5 * FHH + t], p);
        atomicAdd(&out[(size_t)cg * 1024 + 6 * FHH + t], p);
        atomicAdd(&out[(size_t)cg * 1024 + 7 * FHH + t], p);
      }
    }
  }
}

extern "C" void kernel_launch(void* const* d_in, const int* in_sizes, int n_in,
                              void* d_out, int out_size, void* d_ws, size_t ws_size,
                              hipStream_t stream) {
  (void)in_sizes; (void)n_in; (void)ws_size;
  const float* x    = (const float*)d_in[0];
  const int*   ei   = (const int*)d_in[1];
  const int*   bvec = (const int*)d_in[2];
  const float* Wq0  = (const float*)d_in[3];
  const float* bq0  = (const float*)d_in[4];
  const float* Wk0  = (const float*)d_in[5];
  const float* bk0  = (const float*)d_in[6];
  const float* Wv0  = (const float*)d_in[7];
  const float* bv0  = (const float*)d_in[8];
  const float* Ws0  = (const float*)d_in[9];
  const float* bs0  = (const float*)d_in[10];
  const float* WqS  = (const float*)d_in[11];
  const float* bqS  = (const float*)d_in[12];
  const float* WkS  = (const float*)d_in[13];
  const float* bkS  = (const float*)d_in[14];
  const float* WvS  = (const float*)d_in[15];
  const float* bvS  = (const float*)d_in[16];
  const float* WsS  = (const float*)d_in[17];
  const float* bsS  = (const float*)d_in[18];
  const float* gamma = (const float*)d_in[19];
  const float* beta  = (const float*)d_in[20];
  float* out = (float*)d_out;

  char* ws = (char*)d_ws;
  size_t off = 0;
  auto alloc = [&](size_t bytes) {
    void* p = ws + off;
    off = (off + bytes + 255) & ~(size_t)255;
    return p;
  };
  ushort* qbf = (ushort*)alloc((size_t)NN * FHH * 2);
  float* xs   = (float*)alloc((size_t)NN * FHH * 4);
  float* y    = (float*)alloc((size_t)NN * FHH * 4);
  ushort* kv  = (ushort*)alloc((size_t)NN * 256 * 2);
  ushort* Xh  = (ushort*)alloc((size_t)4 * NB * 4096 * 2 + 8192);
  ushort* Xl  = (ushort*)alloc((size_t)4 * NB * 4096 * 2 + 8192);
  uint* colb   = (uint*)alloc((size_t)NE * 4);
  int* row_ptr = (int*)alloc((size_t)(NN + 1) * 4);
  int* cursor  = (int*)alloc((size_t)NN * 4);
  int* deg     = (int*)alloc((size_t)NN * 4);
  int* part    = (int*)alloc((size_t)NCH * 4);
  int* gstart  = (int*)alloc((size_t)(NG + 1) * 4);
  float* bstat = (float*)alloc((size_t)NL * 2 * FHH * 4);
  ushort* wsh = (ushort*)alloc((size_t)360448 * 2);
  ushort* wsl = (ushort*)alloc((size_t)360448 * 2);

  const int* srcv = ei;
  const int* dstv = ei + NE;

  hipMemsetAsync(out, 0, (size_t)out_size * 4, stream);
  hipMemsetAsync(deg, 0, (size_t)NN * 4, stream);
  hipMemsetAsync(bstat, 0, (size_t)NL * 2 * FHH * 4, stream);
  k_gstart<<<5, 64, 0, stream>>>(bvec, gstart);
  k_deg<<<(NE + 255) / 256, 256, 0, stream>>>(dstv, deg);
  k_scanA<<<NCH, 256, 0, stream>>>(deg, part);
  k_scanB<<<1, 64, 0, stream>>>(part, row_ptr);
  k_scanC<<<NCH, 1024, 0, stream>>>(deg, part, row_ptr, cursor);
  k_scatter<<<(NE + 255) / 256, 256, 0, stream>>>(srcv, dstv, cursor, colb);
  k_wconv0<<<128, 256, 0, stream>>>(Wq0, Wk0, Wv0, Ws0, wsh, wsl);
  k_wconvS<<<1280, 256, 0, stream>>>(WqS, WkS, WvS, WsS, wsh, wsl);
  k_presplit<64><<<(NN * 16 + 255) / 256, 256, 0, stream>>>(x, Xh, Xl);

  for (int l = 0; l < NL; ++l) {
    const ushort* WthL = wsh + ((l == 0) ? 0 : (size_t)32768 + (size_t)(l - 1) * 65536);
    const ushort* WtlL = wsl + ((l == 0) ? 0 : (size_t)32768 + (size_t)(l - 1) * 65536);
    const float *bq_, *bk_, *bv_, *bs_;
    if (l == 0) { bq_ = bq0; bk_ = bk0; bv_ = bv0; bs_ = bs0; }
    else {
      size_t bo = (size_t)(l - 1) * FHH;
      bq_ = bqS + bo; bk_ = bkS + bo; bv_ = bvS + bo; bs_ = bsS + bo;
    }
    dim3 gg(NB, 4);
    if (l == 0)
      k_gemm<64><<<gg, 256, 0, stream>>>(Xh, Xl, WthL, WtlL, bq_, bk_, bv_, bs_, qbf, kv, xs);
    else
      k_gemm<128><<<gg, 256, 0, stream>>>(Xh, Xl, WthL, WtlL, bq_, bk_, bv_, bs_, qbf, kv, xs);
    k_agg<<<NN / 4, 256, 0, stream>>>((const uint*)qbf, kv, xs, row_ptr, colb, y);
    float* lsum = bstat + (size_t)l * 2 * FHH;
    float* lsqs = lsum + FHH;
    k_bnstats<<<256, 256, 0, stream>>>(y, lsum, lsqs);
    if (l + 1 < NL)
      k_post<1><<<6250, 256, 0, stream>>>(y, lsum, lsqs, gamma + (size_t)l * FHH,
                                          beta + (size_t)l * FHH, bvec, gstart, out, l, Xh, Xl);
    else
      k_post<0><<<6250, 256, 0, stream>>>(y, lsum, lsqs, gamma + (size_t)l * FHH,
                                          beta + (size_t)l * FHH, bvec, gstart, out, l, Xh, Xl);
  }
}